// Round 10
// baseline (287.801 us; speedup 1.0000x reference)
//
#include <hip/hip_runtime.h>
#include <stdint.h>

// ============================================================================
// CPM layer, bit-exact JAX reproduction. B=8, C=8, H=W=1024.
// Round 10:
//  - prep_fused: js-loop NOT unrolled (I$-resident body; round-9 was 76%
//    VALUBusy on a ~40KB unrolled body). Math identical to round 9.
//  - fused_steps: ALL 8 Metropolis half-steps + out-ch0 finalize in ONE
//    kernel. 2D LDS tile 64x128 + halo 8 (80x144), shrinking update region
//    (ring r valid through step r), code bytes read per step from global.
// RNG / dot / exp / decision-code exprs bit-identical to passing rounds.
// ============================================================================

#define HW    1048576    // 1024*1024
#define BHWu  8388608u   // 8*HW
#define NHu   4194304u   // BHW/2 = packed entries per parity (code plane bytes)

#define TY 64
#define TX 128
#define RY 80            // TY + 2*8
#define RX 144           // TX + 2*8

struct KeysK { uint32_t d[8][2]; uint32_t u[8][2]; };

// ---------------------------------------------------------------------- RNG
__device__ __host__ __forceinline__ void tf2x32(uint32_t k0, uint32_t k1,
                                                uint32_t x0, uint32_t x1,
                                                uint32_t& o0, uint32_t& o1) {
  uint32_t k2 = k0 ^ k1 ^ 0x1BD11BDAu;
  x0 += k0; x1 += k1;
#define RDD(r) { x0 += x1; x1 = (x1 << (r)) | (x1 >> (32 - (r))); x1 ^= x0; }
  RDD(13) RDD(15) RDD(26) RDD(6)
  x0 += k1; x1 += k2 + 1u;
  RDD(17) RDD(29) RDD(16) RDD(24)
  x0 += k2; x1 += k0 + 2u;
  RDD(13) RDD(15) RDD(26) RDD(6)
  x0 += k0; x1 += k1 + 3u;
  RDD(17) RDD(29) RDD(16) RDD(24)
  x0 += k1; x1 += k2 + 4u;
  RDD(13) RDD(15) RDD(26) RDD(6)
  x0 += k2; x1 += k0 + 5u;
#undef RDD
  o0 = x0; o1 = x1;
}

// ------------------------------------------------- XLA-CPU Cephes expf clone
__device__ __forceinline__ float xla_expf(float input) {
  float x  = fmaxf(fminf(input, 88.3762626647950f), -88.3762626647949f);
  float fx = floorf(fmaf(x, 1.44269504088896341f, 0.5f));
  float tmp = __fmul_rn(0.693359375f, fx);
  float z   = __fmul_rn(-2.12194440e-4f, fx);
  x = __fsub_rn(x, tmp);
  x = __fsub_rn(x, z);
  z = __fmul_rn(x, x);
  float y = fmaf(x, 1.9875691500e-4f, 1.3981999507e-3f);
  y = fmaf(y, x, 8.3334519073e-3f);
  y = fmaf(y, x, 4.1665795894e-2f);
  y = fmaf(y, x, 1.6666665459e-1f);
  y = fmaf(y, x, 5.0000001201e-1f);
  y = fmaf(y, z, x);
  y = __fadd_rn(y, 1.0f);
  int n = (int)fx;
  float p2n = __int_as_float((n + 127) << 23);
  return fmaxf(__fmul_rn(y, p2n), input);
}

#define BY(v, i) ((uint32_t)(((v) >> ((i) * 8)) & 0xffu))
// bit-exact accept predicate at integer d (same expr as the step's exp(-dH))
#define ACC_D(dd) (u < xla_expf(-__fadd_rn((float)(dd), v)))

// ------------------------------------------------------------------- kernels
// prep_fused: groups of 15 blocks = 8 compute + 7 copy.
__global__ __launch_bounds__(256) void prep_fused(const float* __restrict__ X,
                                                  const float* __restrict__ W,
                                                  const float* __restrict__ Bb,
                                                  uint8_t* __restrict__ code,
                                                  uint8_t* __restrict__ ids,
                                                  float* __restrict__ out,
                                                  KeysK K) {
  const uint32_t tid = threadIdx.x;
  const uint32_t g = blockIdx.x, group = g / 15u, r = g - group * 15u;
  if (r >= 8u) {                              // ---- copy role (ch1-7)
    uint32_t j = group * 7u + (r - 8u);       // 0..3583
    const float4* X4 = (const float4*)X;
    float4*       O4 = (float4*)out;
#pragma unroll
    for (uint32_t i = 0; i < 16u; i++) {
      uint32_t F = j * 4096u + i * 256u + tid;
      uint32_t b = F / 1835008u;
      uint32_t rem = F - b * 1835008u;
      size_t idx = ((size_t)b << 21) + 262144u + rem;  // b*2^21 + ch1 offset
      O4[idx] = X4[idx];
    }
    return;
  }
  // ---- compute role
  const uint32_t cb    = group * 8u + r;      // 0..4095
  const uint32_t lane  = tid & 127u;
  const uint32_t rhalf = tid >> 7;
  const uint32_t row   = cb * 2u + rhalf;     // 0..8191
  const uint32_t b = row >> 10, y = row & 1023u;
  const uint32_t ylsb = y & 1u;

  const float4* xb = (const float4*)(X + ((size_t)b << 23));
  const uint32_t fq = (y << 8) + 2u * lane;

  float acc[8][4];
  float x0[8];
#pragma unroll
  for (int c = 0; c < 8; c++) {
    float4 a  = xb[((uint32_t)c << 18) + fq];
    float4 bv = xb[((uint32_t)c << 18) + fq + 1u];
    float xs[8] = {a.x, a.y, a.z, a.w, bv.x, bv.y, bv.z, bv.w};
    if (c == 0) {
#pragma unroll
      for (int px = 0; px < 8; px++) x0[px] = xs[px];
    }
#pragma unroll
    for (int px = 0; px < 8; px++)
#pragma unroll
      for (int o = 0; o < 4; o++) {
        float m = __fmul_rn(xs[px], W[o * 8 + c]);
        acc[px][o] = (c == 0) ? __fadd_rn(0.0f, m) : __fadd_rn(acc[px][o], m);
      }
  }
#pragma unroll
  for (int px = 0; px < 8; px++)
#pragma unroll
    for (int o = 0; o < 4; o++) acc[px][o] = __fadd_rn(acc[px][o], Bb[o]);

  {  // ids: 8 bytes packed
    uint32_t lo = ((uint32_t)(uint8_t)(int)x0[0])
                | ((uint32_t)(uint8_t)(int)x0[1] << 8)
                | ((uint32_t)(uint8_t)(int)x0[2] << 16)
                | ((uint32_t)(uint8_t)(int)x0[3] << 24);
    uint32_t hi = ((uint32_t)(uint8_t)(int)x0[4])
                | ((uint32_t)(uint8_t)(int)x0[5] << 8)
                | ((uint32_t)(uint8_t)(int)x0[6] << 16)
                | ((uint32_t)(uint8_t)(int)x0[7] << 24);
    uint2 v2 = {lo, hi};
    *(uint2*)(ids + (b << 20) + (y << 10) + 8u * lane) = v2;
  }

  const uint32_t pbase   = (b << 20) | (y << 10);
  const uint32_t codeoff = (b << 19) | (y << 9) | (4u * lane);
#pragma unroll 1
  for (int js = 0; js < 4; js++) {
#pragma unroll
    for (int pb = 0; pb < 2; pb++) {
      uint32_t s0 = ylsb ^ (uint32_t)pb;      // step t = 2*js + s0
      uint32_t dka = s0 ? K.d[2 * js + 1][0] : K.d[2 * js][0];
      uint32_t dkb = s0 ? K.d[2 * js + 1][1] : K.d[2 * js][1];
      uint32_t uka = s0 ? K.u[2 * js + 1][0] : K.u[2 * js][0];
      uint32_t ukb = s0 ? K.u[2 * js + 1][1] : K.u[2 * js][1];
      uint32_t cword = 0;
#pragma unroll
      for (int k = 0; k < 4; k++) {
        int px = 2 * k + pb;
        uint32_t p = pbase | (8u * lane + (uint32_t)px);
        uint32_t o0, o1, q0, q1;
        tf2x32(dka, dkb, 0u, p, o0, o1);
        uint32_t dir = (o0 ^ o1) & 3u;
        tf2x32(uka, ukb, 0u, p, q0, q1);
        uint32_t ub = (q0 ^ q1) >> 9;
        float u = __fsub_rn(__uint_as_float(ub | 0x3F800000u), 1.0f);
        float v = (dir == 0) ? acc[px][0] : (dir == 1) ? acc[px][1]
                : (dir == 2) ? acc[px][2] : acc[px][3];
        int dstar;
        if (ub == 0u) {                       // u == 0: always accept
          dstar = 4;
        } else {
          // tau = -v - ln(u); total err < ~3e-6 in tau units; band = 1e-4.
          float l2  = __log2f(u);             // v_log_f32
          float tau = fmaf(-0.693147180559945f, l2, -v);
          float gf  = floorf(tau);
          float fr  = tau - gf;
          int   gi  = (int)fmaxf(fminf(gf, 6.0f), -7.0f);
          dstar = gi;
          if (fr < 1e-4f)        dstar = ACC_D(gi)     ? gi     : gi - 1;
          else if (fr > 0.9999f) dstar = ACC_D(gi + 1) ? gi + 1 : gi;
        }
        dstar = dstar < -5 ? -5 : (dstar > 4 ? 4 : dstar);
        cword |= (uint32_t)((uint32_t)(dstar + 5) | (dir << 4)) << (8 * k);
      }
      uint32_t t = 2u * (uint32_t)js + s0;
      *(uint32_t*)(code + (size_t)t * NHu + codeoff) = cword;
    }
  }
}

// fused_steps: all 8 half-steps + out-ch0 finalize in one launch.
// Tile: interior TYxTX, halo 8 each side (torus wrap on load). Update region
// shrinks by 1 ring per step => interior exact after step 7. Accept test is
// the verified byte-code rule: accept <=> dadh+5 <= nibble.
__global__ __launch_bounds__(256) void fused_steps(const uint8_t* __restrict__ ids,
                                                   const uint8_t* __restrict__ code,
                                                   float* __restrict__ out) {
  __shared__ uint8_t T[RY * RX];              // 11520 B
  const uint32_t tid = threadIdx.x;
  const uint32_t blk = blockIdx.x;            // 0..1023
  const uint32_t b  = blk >> 7;               // 8 b
  const uint32_t yt = (blk >> 3) & 15u;       // 16 y-tiles
  const uint32_t xt = blk & 7u;               // 8 x-tiles
  const uint32_t y0 = yt * TY, x0 = xt * TX;

  // load 80x144 halo tile (torus wrap; consecutive i -> coalesced bytes)
  for (uint32_t i = tid; i < RY * RX; i += 256u) {
    uint32_t lr = i / RX, lc = i - lr * RX;
    uint32_t gy = (y0 + lr - 8u) & 1023u;
    uint32_t gx = (x0 + lc - 8u) & 1023u;
    T[i] = ids[(b << 20) | (gy << 10) | gx];
  }
  __syncthreads();

#pragma unroll 1
  for (int t = 0; t < 8; t++) {
    const uint32_t rmin = 1u + (uint32_t)t, rmax = 78u - (uint32_t)t;
    const uint32_t cmin = 1u + (uint32_t)t, cmax = 142u - (uint32_t)t;
    const uint32_t rows = rmax - rmin + 1u;   // 78-2t
    const uint8_t* cp = code + (size_t)t * NHu;
    for (uint32_t k = tid; k < rows * 71u; k += 256u) {
      uint32_t dr = k / 71u;
      uint32_t j  = k - dr * 71u;
      uint32_t lr = rmin + dr;
      uint32_t need = ((uint32_t)t + y0 + x0 + lr) & 1u;   // lc parity
      uint32_t lc0  = cmin + ((cmin ^ need) & 1u);
      uint32_t lc   = lc0 + 2u * j;
      if (lc > cmax) continue;
      uint32_t idx = lr * RX + lc;
      uint32_t self = T[idx];
      uint32_t n0 = T[idx + RX];              // y+1 : roll(-1,0)
      uint32_t n1 = T[idx - RX];              // y-1 : roll(+1,0)
      uint32_t rt = T[idx + 1];               // x+1 : roll(0,-1)
      uint32_t lf = T[idx - 1];               // x-1 : roll(0,+1)
      uint32_t gy = (y0 + lr - 8u) & 1023u;
      uint32_t gx = (x0 + lc - 8u) & 1023u;
      uint32_t bk = cp[(b << 19) | (gy << 9) | (gx >> 1)];
      uint32_t dir = (bk >> 4) & 3u;
      uint32_t ds5 = bk & 15u;
      uint32_t s = (dir == 0) ? n0 : (dir == 1) ? n1 : (dir == 2) ? rt : lf;
      int dadh = ((int)(n0 != s) + (int)(n1 != s) + (int)(rt != s) + (int)(lf != s))
               - ((int)(n0 != self) + (int)(n1 != self) + (int)(rt != self) + (int)(lf != self));
      if ((uint32_t)(dadh + 5) <= ds5) T[idx] = (uint8_t)s;
    }
    __syncthreads();
  }

  // out ch0 <- interior (float4 coalesced)
  float* ob = out + ((size_t)b << 23);
  for (uint32_t k = tid; k < (TY * TX / 4); k += 256u) {   // 2048 float4
    uint32_t row = k >> 5;                    // TX/4 = 32 f4 per row
    uint32_t q   = k & 31u;
    uint32_t idx = (8u + row) * RX + 8u + 4u * q;
    float4 f = { (float)T[idx], (float)T[idx + 1],
                 (float)T[idx + 2], (float)T[idx + 3] };
    ((float4*)(ob + ((y0 + row) << 10) + x0))[q] = f;
  }
}

// ----------------------------------------------- fallback (small-ws) kernels
__device__ __forceinline__ void metro_one(uint32_t u, uint32_t sub,
                                          uint8_t* __restrict__ ids,
                                          const float* __restrict__ dHNN,
                                          uint32_t dk0, uint32_t dk1,
                                          uint32_t uk0, uint32_t uk1) {
  uint32_t b = u >> 19;
  uint32_t r = u & 524287u;
  uint32_t y = r >> 9;
  uint32_t i = r & 511u;
  uint32_t x = (i << 1) | ((y + sub) & 1u);
  uint32_t p = (b << 20) | (y << 10) | x;
  float4 dnn = ((const float4*)dHNN)[sub * NHu + u];
  uint32_t d0, d1, u0, u1;
  tf2x32(dk0, dk1, 0u, p, d0, d1);
  uint32_t db = d0 ^ d1;
  tf2x32(uk0, uk1, 0u, p, u0, u1);
  uint32_t ub = u0 ^ u1;
  int   dir = (int)(db & 3u);
  float uu  = __fsub_rn(__uint_as_float((ub >> 9) | 0x3F800000u), 1.0f);
  uint32_t yN = (y + 1) & 1023u, yP = (y - 1) & 1023u;
  uint32_t xN = (x + 1) & 1023u, xP = (x - 1) & 1023u;
  uint32_t base = b << 20;
  uint32_t cc = ids[p];
  uint32_t n0 = ids[base + (yN << 10) + x];
  uint32_t n1 = ids[base + (yP << 10) + x];
  uint32_t n2 = ids[base + (y << 10) + xN];
  uint32_t n3 = ids[base + (y << 10) + xP];
  uint32_t s  = (dir == 0) ? n0 : (dir == 1) ? n1 : (dir == 2) ? n2 : n3;
  float dH_nn = (dir == 0) ? dnn.x : (dir == 1) ? dnn.y : (dir == 2) ? dnn.z : dnn.w;
  int dadh = ((int)(n0 != s) + (int)(n1 != s) + (int)(n2 != s) + (int)(n3 != s))
           - ((int)(n0 != cc) + (int)(n1 != cc) + (int)(n2 != cc) + (int)(n3 != cc));
  float dH = __fadd_rn((float)dadh, dH_nn);
  if (uu < xla_expf(-dH)) ids[p] = (uint8_t)s;
}

__global__ __launch_bounds__(256) void prep4_fb(const float* __restrict__ X,
                                                const float* __restrict__ W,
                                                const float* __restrict__ Bb,
                                                float* __restrict__ dHNN,
                                                uint8_t* __restrict__ ids) {
  int tid = blockIdx.x * 256 + threadIdx.x;
  int e   = tid << 2;
  int b   = e >> 20;
  int yx  = e & (HW - 1);
  int y   = yx >> 10;
  int x0  = yx & 1023;
  int q4  = yx >> 2;
  const float4* xb = (const float4*)(X + ((size_t)b << 23));
  float4 xc[8];
#pragma unroll
  for (int c = 0; c < 8; c++) xc[c] = xb[(c << 18) + q4];
#pragma unroll
  for (int j = 0; j < 4; j++) {
    float4 r;
#pragma unroll
    for (int o = 0; o < 4; o++) {
      float acc = 0.0f;
#pragma unroll
      for (int c = 0; c < 8; c++)
        acc = __fadd_rn(acc, __fmul_rn(((const float*)&xc[c])[j], W[o * 8 + c]));
      ((float*)&r)[o] = __fadd_rn(acc, Bb[o]);
    }
    int xj = x0 + j;
    ((float4*)dHNN)[((xj + y) & 1) * NHu + (uint32_t)((b << 19) | (y << 9) | (xj >> 1))] = r;
  }
  uchar4 v;
  v.x = (uint8_t)(int)xc[0].x; v.y = (uint8_t)(int)xc[0].y;
  v.z = (uint8_t)(int)xc[0].z; v.w = (uint8_t)(int)xc[0].w;
  *(uchar4*)(ids + e) = v;
}

__global__ __launch_bounds__(256) void half_step_fb(uint8_t* __restrict__ ids,
                                                    const float* __restrict__ dHNN,
                                                    uint32_t dk0, uint32_t dk1,
                                                    uint32_t uk0, uint32_t uk1,
                                                    int sub) {
  uint32_t u = blockIdx.x * 256u + threadIdx.x;
  metro_one(u, (uint32_t)sub, ids, dHNN, dk0, dk1, uk0, uk1);
}

__global__ __launch_bounds__(256) void finalize_full_fb(const float* __restrict__ X,
                                                        const uint8_t* __restrict__ ids,
                                                        float* __restrict__ out) {
  int t = blockIdx.x * 256 + threadIdx.x;
  int e = t << 2;
  int c = (e >> 20) & 7;
  float4 r;
  if (c == 0) {
    int b  = e >> 23;
    int yx = e & (HW - 1);
    uchar4 v = *(const uchar4*)(ids + ((size_t)b << 20) + yx);
    r.x = (float)v.x; r.y = (float)v.y; r.z = (float)v.z; r.w = (float)v.w;
  } else {
    r = ((const float4*)X)[t];
  }
  ((float4*)out)[t] = r;
}

// --------------------------------------------------------------------- host
extern "C" void kernel_launch(void* const* d_in, const int* in_sizes, int n_in,
                              void* d_out, int out_size, void* d_ws, size_t ws_size,
                              hipStream_t stream) {
  const float* X  = (const float*)d_in[0];
  const float* W  = (const float*)d_in[1];
  const float* Bb = (const float*)d_in[2];
  float* out = (float*)d_out;

  const size_t CODE_BYTES = (size_t)NHu * 8u;    // 33.5 MB (8 planes)
  const size_t IDS_BYTES  = (size_t)BHWu;        // 8.4 MB

  // Threefry key chain (partitionable stream; verified rounds 2-9).
  uint32_t bk0 = 0u, bk1 = 42u;
  uint32_t keys[8][2];
  for (uint32_t t = 0; t < 8; t++)
    tf2x32(bk0, bk1, 0u, t, keys[t][0], keys[t][1]);
  uint32_t K[8][4];
  KeysK KK;
  for (int t = 0; t < 8; t++) {
    uint32_t k1a, k1b;
    tf2x32(keys[t][0], keys[t][1], 0u, 0u, k1a, k1b);         // k1 (randint arg)
    tf2x32(keys[t][0], keys[t][1], 0u, 1u, K[t][2], K[t][3]); // k2 -> ukey
    tf2x32(k1a, k1b, 0u, 1u, K[t][0], K[t][1]);               // randint kk2 -> dkey
    KK.d[t][0] = K[t][0]; KK.d[t][1] = K[t][1];
    KK.u[t][0] = K[t][2]; KK.u[t][1] = K[t][3];
  }

  bool ws_ok = ws_size >= CODE_BYTES + IDS_BYTES;
  if (ws_ok) {
    uint8_t* code = (uint8_t*)d_ws;
    uint8_t* ids  = (uint8_t*)d_ws + CODE_BYTES;

    prep_fused<<<7680, 256, 0, stream>>>(X, W, Bb, code, ids, out, KK);
    fused_steps<<<1024, 256, 0, stream>>>(ids, code, out);
  } else {
    float*   dHNN = out;                 // dHNN lives in out; ids in ws
    uint8_t* ids  = (uint8_t*)d_ws;
    prep4_fb<<<8192, 256, 0, stream>>>(X, W, Bb, dHNN, ids);
    for (int t = 0; t < 8; t++)
      half_step_fb<<<16384, 256, 0, stream>>>(ids, dHNN,
          K[t][0], K[t][1], K[t][2], K[t][3], t & 1);
    finalize_full_fb<<<65536, 256, 0, stream>>>(X, ids, out);
  }
  (void)in_sizes; (void)n_in; (void)out_size;
}

// Round 11
// 238.017 us; speedup vs baseline: 1.2092x; 1.2092x over previous
//
#include <hip/hip_runtime.h>
#include <stdint.h>

// ============================================================================
// CPM layer, bit-exact JAX reproduction. B=8, C=8, H=W=1024.
// Round 11:
//  - steps reverted to step_d (round-9 verified, ~7.8us each); fused_steps
//    LDS-byte stencil was slower (80us) than 8 launches (62us).
//  - prep_fused4: 4 px/thread (was 8) -> unrolled text ~19KB (I$-resident)
//    and 2x thread-level parallelism to hide load/store latency under the
//    threefry VALU chain. Copy fused at 16:7 compute:copy blocks.
// RNG / dot / exp / certainty-band decision code bit-identical to rounds 2-10.
// ============================================================================

#define HW    1048576    // 1024*1024
#define BHWu  8388608u   // 8*HW
#define NHu   4194304u   // BHW/2 = packed entries per parity (code plane bytes)

struct KeysK { uint32_t d[8][2]; uint32_t u[8][2]; };

// ---------------------------------------------------------------------- RNG
__device__ __host__ __forceinline__ void tf2x32(uint32_t k0, uint32_t k1,
                                                uint32_t x0, uint32_t x1,
                                                uint32_t& o0, uint32_t& o1) {
  uint32_t k2 = k0 ^ k1 ^ 0x1BD11BDAu;
  x0 += k0; x1 += k1;
#define RDD(r) { x0 += x1; x1 = (x1 << (r)) | (x1 >> (32 - (r))); x1 ^= x0; }
  RDD(13) RDD(15) RDD(26) RDD(6)
  x0 += k1; x1 += k2 + 1u;
  RDD(17) RDD(29) RDD(16) RDD(24)
  x0 += k2; x1 += k0 + 2u;
  RDD(13) RDD(15) RDD(26) RDD(6)
  x0 += k0; x1 += k1 + 3u;
  RDD(17) RDD(29) RDD(16) RDD(24)
  x0 += k1; x1 += k2 + 4u;
  RDD(13) RDD(15) RDD(26) RDD(6)
  x0 += k2; x1 += k0 + 5u;
#undef RDD
  o0 = x0; o1 = x1;
}

// ------------------------------------------------- XLA-CPU Cephes expf clone
__device__ __forceinline__ float xla_expf(float input) {
  float x  = fmaxf(fminf(input, 88.3762626647950f), -88.3762626647949f);
  float fx = floorf(fmaf(x, 1.44269504088896341f, 0.5f));
  float tmp = __fmul_rn(0.693359375f, fx);
  float z   = __fmul_rn(-2.12194440e-4f, fx);
  x = __fsub_rn(x, tmp);
  x = __fsub_rn(x, z);
  z = __fmul_rn(x, x);
  float y = fmaf(x, 1.9875691500e-4f, 1.3981999507e-3f);
  y = fmaf(y, x, 8.3334519073e-3f);
  y = fmaf(y, x, 4.1665795894e-2f);
  y = fmaf(y, x, 1.6666665459e-1f);
  y = fmaf(y, x, 5.0000001201e-1f);
  y = fmaf(y, z, x);
  y = __fadd_rn(y, 1.0f);
  int n = (int)fx;
  float p2n = __int_as_float((n + 127) << 23);
  return fmaxf(__fmul_rn(y, p2n), input);
}

#define BY(v, i) ((uint32_t)(((v) >> ((i) * 8)) & 0xffu))
// bit-exact accept predicate at integer d (same expr as the step's exp(-dH))
#define ACC_D(dd) (u < xla_expf(-__fadd_rn((float)(dd), v)))

// ------------------------------------------------------------------- kernels
// prep_fused4: groups of 23 blocks = 16 compute + 7 copy.
//  compute: 1 row/block, 4 px/thread. Per px: dot (Eigen no-FMA chain),
//   per active step: dir cipher + uniform cipher + certainty-band code byte.
//  copy: 16 float4/thread of the X ch1-7 -> out pass-through.
__global__ __launch_bounds__(256) void prep_fused4(const float* __restrict__ X,
                                                   const float* __restrict__ W,
                                                   const float* __restrict__ Bb,
                                                   uint8_t* __restrict__ code,
                                                   uint8_t* __restrict__ ids,
                                                   float* __restrict__ out,
                                                   KeysK K) {
  const uint32_t tid = threadIdx.x;
  const uint32_t g = blockIdx.x, group = g / 23u, r = g - group * 23u;
  if (r >= 16u) {                             // ---- copy role (ch1-7)
    uint32_t j = group * 7u + (r - 16u);      // 0..3583
    const float4* X4 = (const float4*)X;
    float4*       O4 = (float4*)out;
#pragma unroll
    for (uint32_t i = 0; i < 16u; i++) {
      uint32_t F = j * 4096u + i * 256u + tid;       // < 14,680,064
      uint32_t b = F / 1835008u;
      uint32_t rem = F - b * 1835008u;
      size_t idx = ((size_t)b << 21) + 262144u + rem;  // b*2^21 + ch1 offset
      O4[idx] = X4[idx];
    }
    return;
  }
  // ---- compute role: one row per block, 4 px per thread
  const uint32_t row = group * 16u + r;       // 0..8191
  const uint32_t b = row >> 10, y = row & 1023u;
  const uint32_t ylsb = y & 1u;
  const uint32_t x0 = 4u * tid;

  const float4* xb = (const float4*)(X + ((size_t)b << 23));
  const uint32_t fq = (y << 8) + tid;         // float4 idx within plane

  float acc[4][4];
  float c0[4];
#pragma unroll
  for (int c = 0; c < 8; c++) {
    float4 a = xb[((uint32_t)c << 18) + fq];
    float xs[4] = {a.x, a.y, a.z, a.w};
    if (c == 0) {
#pragma unroll
      for (int px = 0; px < 4; px++) c0[px] = xs[px];
    }
#pragma unroll
    for (int px = 0; px < 4; px++)
#pragma unroll
      for (int o = 0; o < 4; o++) {
        float m = __fmul_rn(xs[px], W[o * 8 + c]);
        acc[px][o] = (c == 0) ? __fadd_rn(0.0f, m) : __fadd_rn(acc[px][o], m);
      }
  }
#pragma unroll
  for (int px = 0; px < 4; px++)
#pragma unroll
    for (int o = 0; o < 4; o++) acc[px][o] = __fadd_rn(acc[px][o], Bb[o]);

  {  // ids: 4 bytes packed
    uchar4 v;
    v.x = (uint8_t)(int)c0[0]; v.y = (uint8_t)(int)c0[1];
    v.z = (uint8_t)(int)c0[2]; v.w = (uint8_t)(int)c0[3];
    *(uchar4*)(ids + (b << 20) + (y << 10) + x0) = v;
  }

  const uint32_t pbase   = (b << 20) | (y << 10);
  const uint32_t codeoff = (b << 19) | (y << 9) | (x0 >> 1);
#pragma unroll
  for (int js = 0; js < 4; js++) {
#pragma unroll
    for (int pb = 0; pb < 2; pb++) {
      uint32_t s0 = ylsb ^ (uint32_t)pb;      // step t = 2*js + s0
      uint32_t dka = s0 ? K.d[2 * js + 1][0] : K.d[2 * js][0];
      uint32_t dkb = s0 ? K.d[2 * js + 1][1] : K.d[2 * js][1];
      uint32_t uka = s0 ? K.u[2 * js + 1][0] : K.u[2 * js][0];
      uint32_t ukb = s0 ? K.u[2 * js + 1][1] : K.u[2 * js][1];
      uint32_t cword = 0;
#pragma unroll
      for (int k = 0; k < 2; k++) {
        int px = 2 * k + pb;
        uint32_t p = pbase | (x0 + (uint32_t)px);
        uint32_t o0, o1, q0, q1;
        tf2x32(dka, dkb, 0u, p, o0, o1);
        uint32_t dir = (o0 ^ o1) & 3u;
        tf2x32(uka, ukb, 0u, p, q0, q1);
        uint32_t ub = (q0 ^ q1) >> 9;
        float u = __fsub_rn(__uint_as_float(ub | 0x3F800000u), 1.0f);
        float v = (dir == 0) ? acc[px][0] : (dir == 1) ? acc[px][1]
                : (dir == 2) ? acc[px][2] : acc[px][3];
        int dstar;
        if (ub == 0u) {                       // u == 0: always accept
          dstar = 4;
        } else {
          // tau = -v - ln(u); total err < ~3e-6 in tau units; band = 1e-4.
          float l2  = __log2f(u);             // v_log_f32
          float tau = fmaf(-0.693147180559945f, l2, -v);
          float gf  = floorf(tau);
          float fr  = tau - gf;
          int   gi  = (int)fmaxf(fminf(gf, 6.0f), -7.0f);
          dstar = gi;
          if (fr < 1e-4f)        dstar = ACC_D(gi)     ? gi     : gi - 1;
          else if (fr > 0.9999f) dstar = ACC_D(gi + 1) ? gi + 1 : gi;
        }
        dstar = dstar < -5 ? -5 : (dstar > 4 ? 4 : dstar);
        cword |= (uint32_t)((uint32_t)(dstar + 5) | (dir << 4)) << (8 * k);
      }
      uint32_t t = 2u * (uint32_t)js + s0;
      *(uint16_t*)(code + (size_t)t * NHu + codeoff) = (uint16_t)cword;
    }
  }
}

// step_d: pure byte logic (round-9 verified). 4 active px/thread;
// accept <=> dadh+5 <= nibble. LAST=1: write out-ch0 for the 8-px span.
template <int LAST>
__global__ __launch_bounds__(256) void step_d(uint8_t* __restrict__ ids,
                                              const uint8_t* __restrict__ codeT,
                                              float* __restrict__ out,
                                              int subi) {
  uint32_t n   = blockIdx.x * 256u + (uint32_t)threadIdx.x;  // 0 .. 2^20-1
  uint32_t sub = (uint32_t)subi;
  uint32_t b   = n >> 17;
  uint32_t y   = (n >> 7) & 1023u;
  uint32_t c   = (y + sub) & 1u;
  uint32_t X8  = (n & 127u) << 3;
  uint32_t rowp = (b << 20) | (y << 10);
  uint32_t upp  = (b << 20) | (((y + 1u) & 1023u) << 10);
  uint32_t dnp  = (b << 20) | (((y - 1u) & 1023u) << 10);

  uint32_t cw = *(const uint32_t*)(codeT + ((b << 19) | (y << 9) | ((n & 127u) << 2)));

  uint64_t mid = *(const uint64_t*)(ids + rowp + X8);
  uint64_t up  = *(const uint64_t*)(ids + upp + X8);
  uint64_t dn  = *(const uint64_t*)(ids + dnp + X8);
  uint32_t e   = c ? (uint32_t)ids[rowp + ((X8 + 8u) & 1023u)]
                   : (uint32_t)ids[rowp + ((X8 + 1023u) & 1023u)];

  uint32_t nw[4];
#pragma unroll
  for (int k = 0; k < 4; k++) {
    uint32_t self  = c ? BY(mid, 2 * k + 1) : BY(mid, 2 * k);
    uint32_t left  = c ? BY(mid, 2 * k)
                       : ((k == 0) ? e : BY(mid, 2 * k - 1));
    uint32_t right = c ? ((k == 3) ? e : BY(mid, 2 * k + 2))
                       : BY(mid, 2 * k + 1);
    uint32_t n0 = c ? BY(up, 2 * k + 1) : BY(up, 2 * k);   // roll(-1,0): y+1
    uint32_t n1 = c ? BY(dn, 2 * k + 1) : BY(dn, 2 * k);   // roll(+1,0): y-1

    uint32_t bk  = (cw >> (8 * k)) & 0xffu;
    uint32_t dir = (bk >> 4) & 3u;
    uint32_t ds5 = bk & 15u;
    uint32_t s  = (dir == 0) ? n0 : (dir == 1) ? n1 : (dir == 2) ? right : left;
    int dadh = ((int)(n0 != s) + (int)(n1 != s) + (int)(right != s) + (int)(left != s))
             - ((int)(n0 != self) + (int)(n1 != self) + (int)(right != self) + (int)(left != self));
    nw[k] = ((uint32_t)(dadh + 5) <= ds5) ? s : self;
  }

  if (!LAST) {
    uint64_t A = (uint64_t)nw[0] | ((uint64_t)nw[1] << 16)
               | ((uint64_t)nw[2] << 32) | ((uint64_t)nw[3] << 48);
    uint64_t mask = 0x00FF00FF00FF00FFull << (8u * c);
    uint64_t nm = (mid & ~mask) | (A << (8u * c));
    *(uint64_t*)(ids + rowp + X8) = nm;
  } else {
    float f[8];
#pragma unroll
    for (int j = 0; j < 8; j++) {
      uint32_t bj = (((uint32_t)j & 1u) == c) ? nw[j >> 1] : BY(mid, j);
      f[j] = (float)bj;
    }
    float4 f0 = {f[0], f[1], f[2], f[3]};
    float4 f1 = {f[4], f[5], f[6], f[7]};
    float* op = out + ((size_t)b << 23) + (y << 10) + X8;
    *(float4*)op       = f0;
    *(float4*)(op + 4) = f1;
  }
}

// ----------------------------------------------- fallback (small-ws) kernels
__device__ __forceinline__ void metro_one(uint32_t u, uint32_t sub,
                                          uint8_t* __restrict__ ids,
                                          const float* __restrict__ dHNN,
                                          uint32_t dk0, uint32_t dk1,
                                          uint32_t uk0, uint32_t uk1) {
  uint32_t b = u >> 19;
  uint32_t r = u & 524287u;
  uint32_t y = r >> 9;
  uint32_t i = r & 511u;
  uint32_t x = (i << 1) | ((y + sub) & 1u);
  uint32_t p = (b << 20) | (y << 10) | x;
  float4 dnn = ((const float4*)dHNN)[sub * NHu + u];
  uint32_t d0, d1, u0, u1;
  tf2x32(dk0, dk1, 0u, p, d0, d1);
  uint32_t db = d0 ^ d1;
  tf2x32(uk0, uk1, 0u, p, u0, u1);
  uint32_t ub = u0 ^ u1;
  int   dir = (int)(db & 3u);
  float uu  = __fsub_rn(__uint_as_float((ub >> 9) | 0x3F800000u), 1.0f);
  uint32_t yN = (y + 1) & 1023u, yP = (y - 1) & 1023u;
  uint32_t xN = (x + 1) & 1023u, xP = (x - 1) & 1023u;
  uint32_t base = b << 20;
  uint32_t cc = ids[p];
  uint32_t n0 = ids[base + (yN << 10) + x];
  uint32_t n1 = ids[base + (yP << 10) + x];
  uint32_t n2 = ids[base + (y << 10) + xN];
  uint32_t n3 = ids[base + (y << 10) + xP];
  uint32_t s  = (dir == 0) ? n0 : (dir == 1) ? n1 : (dir == 2) ? n2 : n3;
  float dH_nn = (dir == 0) ? dnn.x : (dir == 1) ? dnn.y : (dir == 2) ? dnn.z : dnn.w;
  int dadh = ((int)(n0 != s) + (int)(n1 != s) + (int)(n2 != s) + (int)(n3 != s))
           - ((int)(n0 != cc) + (int)(n1 != cc) + (int)(n2 != cc) + (int)(n3 != cc));
  float dH = __fadd_rn((float)dadh, dH_nn);
  if (uu < xla_expf(-dH)) ids[p] = (uint8_t)s;
}

__global__ __launch_bounds__(256) void prep4_fb(const float* __restrict__ X,
                                                const float* __restrict__ W,
                                                const float* __restrict__ Bb,
                                                float* __restrict__ dHNN,
                                                uint8_t* __restrict__ ids) {
  int tid = blockIdx.x * 256 + threadIdx.x;
  int e   = tid << 2;
  int b   = e >> 20;
  int yx  = e & (HW - 1);
  int y   = yx >> 10;
  int x0  = yx & 1023;
  int q4  = yx >> 2;
  const float4* xb = (const float4*)(X + ((size_t)b << 23));
  float4 xc[8];
#pragma unroll
  for (int c = 0; c < 8; c++) xc[c] = xb[(c << 18) + q4];
#pragma unroll
  for (int j = 0; j < 4; j++) {
    float4 r;
#pragma unroll
    for (int o = 0; o < 4; o++) {
      float acc = 0.0f;
#pragma unroll
      for (int c = 0; c < 8; c++)
        acc = __fadd_rn(acc, __fmul_rn(((const float*)&xc[c])[j], W[o * 8 + c]));
      ((float*)&r)[o] = __fadd_rn(acc, Bb[o]);
    }
    int xj = x0 + j;
    ((float4*)dHNN)[((xj + y) & 1) * NHu + (uint32_t)((b << 19) | (y << 9) | (xj >> 1))] = r;
  }
  uchar4 v;
  v.x = (uint8_t)(int)xc[0].x; v.y = (uint8_t)(int)xc[0].y;
  v.z = (uint8_t)(int)xc[0].z; v.w = (uint8_t)(int)xc[0].w;
  *(uchar4*)(ids + e) = v;
}

__global__ __launch_bounds__(256) void half_step_fb(uint8_t* __restrict__ ids,
                                                    const float* __restrict__ dHNN,
                                                    uint32_t dk0, uint32_t dk1,
                                                    uint32_t uk0, uint32_t uk1,
                                                    int sub) {
  uint32_t u = blockIdx.x * 256u + threadIdx.x;
  metro_one(u, (uint32_t)sub, ids, dHNN, dk0, dk1, uk0, uk1);
}

__global__ __launch_bounds__(256) void finalize_full_fb(const float* __restrict__ X,
                                                        const uint8_t* __restrict__ ids,
                                                        float* __restrict__ out) {
  int t = blockIdx.x * 256 + threadIdx.x;
  int e = t << 2;
  int c = (e >> 20) & 7;
  float4 r;
  if (c == 0) {
    int b  = e >> 23;
    int yx = e & (HW - 1);
    uchar4 v = *(const uchar4*)(ids + ((size_t)b << 20) + yx);
    r.x = (float)v.x; r.y = (float)v.y; r.z = (float)v.z; r.w = (float)v.w;
  } else {
    r = ((const float4*)X)[t];
  }
  ((float4*)out)[t] = r;
}

// --------------------------------------------------------------------- host
extern "C" void kernel_launch(void* const* d_in, const int* in_sizes, int n_in,
                              void* d_out, int out_size, void* d_ws, size_t ws_size,
                              hipStream_t stream) {
  const float* X  = (const float*)d_in[0];
  const float* W  = (const float*)d_in[1];
  const float* Bb = (const float*)d_in[2];
  float* out = (float*)d_out;

  const size_t CODE_BYTES = (size_t)NHu * 8u;    // 33.5 MB (8 planes)
  const size_t IDS_BYTES  = (size_t)BHWu;        // 8.4 MB

  // Threefry key chain (partitionable stream; verified rounds 2-10).
  uint32_t bk0 = 0u, bk1 = 42u;
  uint32_t keys[8][2];
  for (uint32_t t = 0; t < 8; t++)
    tf2x32(bk0, bk1, 0u, t, keys[t][0], keys[t][1]);
  uint32_t K[8][4];
  KeysK KK;
  for (int t = 0; t < 8; t++) {
    uint32_t k1a, k1b;
    tf2x32(keys[t][0], keys[t][1], 0u, 0u, k1a, k1b);         // k1 (randint arg)
    tf2x32(keys[t][0], keys[t][1], 0u, 1u, K[t][2], K[t][3]); // k2 -> ukey
    tf2x32(k1a, k1b, 0u, 1u, K[t][0], K[t][1]);               // randint kk2 -> dkey
    KK.d[t][0] = K[t][0]; KK.d[t][1] = K[t][1];
    KK.u[t][0] = K[t][2]; KK.u[t][1] = K[t][3];
  }

  bool ws_ok = ws_size >= CODE_BYTES + IDS_BYTES;
  if (ws_ok) {
    uint8_t* code = (uint8_t*)d_ws;
    uint8_t* ids  = (uint8_t*)d_ws + CODE_BYTES;

    prep_fused4<<<11776, 256, 0, stream>>>(X, W, Bb, code, ids, out, KK);
    for (int t = 0; t < 7; t++)
      step_d<0><<<4096, 256, 0, stream>>>(ids, code + (size_t)t * NHu, out, t & 1);
    step_d<1><<<4096, 256, 0, stream>>>(ids, code + (size_t)7 * NHu, out, 1);
  } else {
    float*   dHNN = out;                 // dHNN lives in out; ids in ws
    uint8_t* ids  = (uint8_t*)d_ws;
    prep4_fb<<<8192, 256, 0, stream>>>(X, W, Bb, dHNN, ids);
    for (int t = 0; t < 8; t++)
      half_step_fb<<<16384, 256, 0, stream>>>(ids, dHNN,
          K[t][0], K[t][1], K[t][2], K[t][3], t & 1);
    finalize_full_fb<<<65536, 256, 0, stream>>>(X, ids, out);
  }
  (void)in_sizes; (void)n_in; (void)out_size;
}

// Round 12
// 229.083 us; speedup vs baseline: 1.2563x; 1.0390x over previous
//
#include <hip/hip_runtime.h>
#include <stdint.h>

// ============================================================================
// CPM layer, bit-exact JAX reproduction. B=8, C=8, H=W=1024.
// Round 12:
//  - tf2x32 rotates forced to v_alignbit_b32 on device (bit-exact).
//  - step2_d: TWO half-steps per launch, ping-pong ids buffers (no in-place
//    races). Thread recomputes step-ta for rows y-1,y,y+1 plus the one
//    boundary byte E in registers, then step-tb for row y. 4 launches.
// RNG / dot / exp / certainty-band decision code bit-identical to rounds 2-11.
// ============================================================================

#define HW    1048576    // 1024*1024
#define BHWu  8388608u   // 8*HW
#define NHu   4194304u   // BHW/2 = code plane bytes

struct KeysK { uint32_t d[8][2]; uint32_t u[8][2]; };

// ---------------------------------------------------------------------- RNG
#ifdef __HIP_DEVICE_COMPILE__
#define ROTL(v, r) __builtin_amdgcn_alignbit((v), (v), 32u - (r))
#else
#define ROTL(v, r) (((v) << (r)) | ((v) >> (32 - (r))))
#endif

__device__ __host__ __forceinline__ void tf2x32(uint32_t k0, uint32_t k1,
                                                uint32_t x0, uint32_t x1,
                                                uint32_t& o0, uint32_t& o1) {
  uint32_t k2 = k0 ^ k1 ^ 0x1BD11BDAu;
  x0 += k0; x1 += k1;
#define RDD(r) { x0 += x1; x1 = ROTL(x1, r) ^ x0; }
  RDD(13) RDD(15) RDD(26) RDD(6)
  x0 += k1; x1 += k2 + 1u;
  RDD(17) RDD(29) RDD(16) RDD(24)
  x0 += k2; x1 += k0 + 2u;
  RDD(13) RDD(15) RDD(26) RDD(6)
  x0 += k0; x1 += k1 + 3u;
  RDD(17) RDD(29) RDD(16) RDD(24)
  x0 += k1; x1 += k2 + 4u;
  RDD(13) RDD(15) RDD(26) RDD(6)
  x0 += k2; x1 += k0 + 5u;
#undef RDD
  o0 = x0; o1 = x1;
}

// ------------------------------------------------- XLA-CPU Cephes expf clone
__device__ __forceinline__ float xla_expf(float input) {
  float x  = fmaxf(fminf(input, 88.3762626647950f), -88.3762626647949f);
  float fx = floorf(fmaf(x, 1.44269504088896341f, 0.5f));
  float tmp = __fmul_rn(0.693359375f, fx);
  float z   = __fmul_rn(-2.12194440e-4f, fx);
  x = __fsub_rn(x, tmp);
  x = __fsub_rn(x, z);
  z = __fmul_rn(x, x);
  float y = fmaf(x, 1.9875691500e-4f, 1.3981999507e-3f);
  y = fmaf(y, x, 8.3334519073e-3f);
  y = fmaf(y, x, 4.1665795894e-2f);
  y = fmaf(y, x, 1.6666665459e-1f);
  y = fmaf(y, x, 5.0000001201e-1f);
  y = fmaf(y, z, x);
  y = __fadd_rn(y, 1.0f);
  int n = (int)fx;
  float p2n = __int_as_float((n + 127) << 23);
  return fmaxf(__fmul_rn(y, p2n), input);
}

#define BY(v, i) ((uint32_t)(((v) >> ((i) * 8)) & 0xffu))
#define ACC_D(dd) (u < xla_expf(-__fadd_rn((float)(dd), v)))

// ------------------------------------------------------------------- kernels
// prep_fused4: groups of 23 blocks = 16 compute + 7 copy (round-11 verified).
__global__ __launch_bounds__(256) void prep_fused4(const float* __restrict__ X,
                                                   const float* __restrict__ W,
                                                   const float* __restrict__ Bb,
                                                   uint8_t* __restrict__ code,
                                                   uint8_t* __restrict__ ids,
                                                   float* __restrict__ out,
                                                   KeysK K) {
  const uint32_t tid = threadIdx.x;
  const uint32_t g = blockIdx.x, group = g / 23u, r = g - group * 23u;
  if (r >= 16u) {                             // ---- copy role (ch1-7)
    uint32_t j = group * 7u + (r - 16u);      // 0..3583
    const float4* X4 = (const float4*)X;
    float4*       O4 = (float4*)out;
#pragma unroll
    for (uint32_t i = 0; i < 16u; i++) {
      uint32_t F = j * 4096u + i * 256u + tid;       // < 14,680,064
      uint32_t b = F / 1835008u;
      uint32_t rem = F - b * 1835008u;
      size_t idx = ((size_t)b << 21) + 262144u + rem;  // b*2^21 + ch1 offset
      O4[idx] = X4[idx];
    }
    return;
  }
  // ---- compute role: one row per block, 4 px per thread
  const uint32_t row = group * 16u + r;       // 0..8191
  const uint32_t b = row >> 10, y = row & 1023u;
  const uint32_t ylsb = y & 1u;
  const uint32_t x0 = 4u * tid;

  const float4* xb = (const float4*)(X + ((size_t)b << 23));
  const uint32_t fq = (y << 8) + tid;

  float acc[4][4];
  float c0[4];
#pragma unroll
  for (int c = 0; c < 8; c++) {
    float4 a = xb[((uint32_t)c << 18) + fq];
    float xs[4] = {a.x, a.y, a.z, a.w};
    if (c == 0) {
#pragma unroll
      for (int px = 0; px < 4; px++) c0[px] = xs[px];
    }
#pragma unroll
    for (int px = 0; px < 4; px++)
#pragma unroll
      for (int o = 0; o < 4; o++) {
        float m = __fmul_rn(xs[px], W[o * 8 + c]);
        acc[px][o] = (c == 0) ? __fadd_rn(0.0f, m) : __fadd_rn(acc[px][o], m);
      }
  }
#pragma unroll
  for (int px = 0; px < 4; px++)
#pragma unroll
    for (int o = 0; o < 4; o++) acc[px][o] = __fadd_rn(acc[px][o], Bb[o]);

  {  // ids: 4 bytes packed
    uchar4 v;
    v.x = (uint8_t)(int)c0[0]; v.y = (uint8_t)(int)c0[1];
    v.z = (uint8_t)(int)c0[2]; v.w = (uint8_t)(int)c0[3];
    *(uchar4*)(ids + (b << 20) + (y << 10) + x0) = v;
  }

  const uint32_t pbase   = (b << 20) | (y << 10);
  const uint32_t codeoff = (b << 19) | (y << 9) | (x0 >> 1);
#pragma unroll
  for (int js = 0; js < 4; js++) {
#pragma unroll
    for (int pb = 0; pb < 2; pb++) {
      uint32_t s0 = ylsb ^ (uint32_t)pb;      // step t = 2*js + s0
      uint32_t dka = s0 ? K.d[2 * js + 1][0] : K.d[2 * js][0];
      uint32_t dkb = s0 ? K.d[2 * js + 1][1] : K.d[2 * js][1];
      uint32_t uka = s0 ? K.u[2 * js + 1][0] : K.u[2 * js][0];
      uint32_t ukb = s0 ? K.u[2 * js + 1][1] : K.u[2 * js][1];
      uint32_t cword = 0;
#pragma unroll
      for (int k = 0; k < 2; k++) {
        int px = 2 * k + pb;
        uint32_t p = pbase | (x0 + (uint32_t)px);
        uint32_t o0, o1, q0, q1;
        tf2x32(dka, dkb, 0u, p, o0, o1);
        uint32_t dir = (o0 ^ o1) & 3u;
        tf2x32(uka, ukb, 0u, p, q0, q1);
        uint32_t ub = (q0 ^ q1) >> 9;
        float u = __fsub_rn(__uint_as_float(ub | 0x3F800000u), 1.0f);
        float v = (dir == 0) ? acc[px][0] : (dir == 1) ? acc[px][1]
                : (dir == 2) ? acc[px][2] : acc[px][3];
        int dstar;
        if (ub == 0u) {                       // u == 0: always accept
          dstar = 4;
        } else {
          float l2  = __log2f(u);             // v_log_f32
          float tau = fmaf(-0.693147180559945f, l2, -v);
          float gf  = floorf(tau);
          float fr  = tau - gf;
          int   gi  = (int)fmaxf(fminf(gf, 6.0f), -7.0f);
          dstar = gi;
          if (fr < 1e-4f)        dstar = ACC_D(gi)     ? gi     : gi - 1;
          else if (fr > 0.9999f) dstar = ACC_D(gi + 1) ? gi + 1 : gi;
        }
        dstar = dstar < -5 ? -5 : (dstar > 4 ? 4 : dstar);
        cword |= (uint32_t)((uint32_t)(dstar + 5) | (dir << 4)) << (8 * k);
      }
      uint32_t t = 2u * (uint32_t)js + s0;
      *(uint16_t*)(code + (size_t)t * NHu + codeoff) = (uint16_t)cword;
    }
  }
}

// --------------------------------------------------- fused double-step logic
__device__ __forceinline__ uint32_t upd1(uint32_t self, uint32_t n0, uint32_t n1,
                                         uint32_t rt, uint32_t lf, uint32_t bk) {
  uint32_t dir = (bk >> 4) & 3u;
  uint32_t ds5 = bk & 15u;
  uint32_t s = (dir == 0) ? n0 : (dir == 1) ? n1 : (dir == 2) ? rt : lf;
  int dadh = ((int)(n0 != s) + (int)(n1 != s) + (int)(rt != s) + (int)(lf != s))
           - ((int)(n0 != self) + (int)(n1 != self) + (int)(rt != self) + (int)(lf != self));
  return ((uint32_t)(dadh + 5) <= ds5) ? s : self;
}

// one even-parity-step row update: 4 actives at x=X8+2k+c; e = edge byte
// (right edge X8+8 if c==1, left edge X8-1 if c==0). Matches step_d exactly.
__device__ __forceinline__ void upd_row(uint64_t mid, uint64_t up, uint64_t dn,
                                        uint32_t e, uint32_t c, uint32_t cw,
                                        uint32_t nw[4]) {
#pragma unroll
  for (int k = 0; k < 4; k++) {
    uint32_t self  = c ? BY(mid, 2 * k + 1) : BY(mid, 2 * k);
    uint32_t left  = c ? BY(mid, 2 * k)
                       : ((k == 0) ? e : BY(mid, 2 * k - 1));
    uint32_t right = c ? ((k == 3) ? e : BY(mid, 2 * k + 2))
                       : BY(mid, 2 * k + 1);
    uint32_t n0 = c ? BY(up, 2 * k + 1) : BY(up, 2 * k);   // roll(-1,0): y+1
    uint32_t n1 = c ? BY(dn, 2 * k + 1) : BY(dn, 2 * k);   // roll(+1,0): y-1
    nw[k] = upd1(self, n0, n1, right, left, (cw >> (8 * k)) & 0xffu);
  }
}

// step2_d: steps ta (even, sub=0) and ta+1 (sub=1) fused; reads `in`,
// writes `outids` (ping-pong; no in-place hazards). Thread owns the 8-px
// span (b,y,X8..X8+7): recomputes ta for rows y-1,y,y+1 and boundary byte E,
// then tb for row y. LAST=1: write out-ch0 floats instead of ids.
template <int LAST>
__global__ __launch_bounds__(256) void step2_d(const uint8_t* __restrict__ in,
                                               uint8_t* __restrict__ outids,
                                               const uint8_t* __restrict__ codeA,
                                               const uint8_t* __restrict__ codeB,
                                               float* __restrict__ out) {
  uint32_t n  = blockIdx.x * 256u + (uint32_t)threadIdx.x;   // 0 .. 2^20-1
  uint32_t b  = n >> 17;
  uint32_t y  = (n >> 7) & 1023u;
  uint32_t X8 = (n & 127u) << 3;
  uint32_t base = b << 20;
  uint32_t ym2 = (y - 2u) & 1023u, ym1 = (y - 1u) & 1023u;
  uint32_t yp1 = (y + 1u) & 1023u, yp2 = (y + 2u) & 1023u;
  uint32_t c_a = y & 1u;          // ta (sub=0) active x-parity in row y
  uint32_t c_b = 1u - c_a;        // tb (sub=1) active x-parity in row y
                                   // (rows y±1 have ta-active parity c_b)

  uint64_t pm2 = *(const uint64_t*)(in + base + (ym2 << 10) + X8);
  uint64_t pm1 = *(const uint64_t*)(in + base + (ym1 << 10) + X8);
  uint64_t p0  = *(const uint64_t*)(in + base + (y   << 10) + X8);
  uint64_t pp1 = *(const uint64_t*)(in + base + (yp1 << 10) + X8);
  uint64_t pp2 = *(const uint64_t*)(in + base + (yp2 << 10) + X8);

  uint32_t exL = (X8 + 1023u) & 1023u;          // X8-1
  uint32_t exR = (X8 + 8u) & 1023u;             // X8+8
  uint32_t xe  = c_b ? exR : exL;               // tb boundary / rows y±1 ta edge
  uint32_t yeA = c_a ? exR : exL;               // row y ta edge (opposite side)
  uint32_t xo  = c_b ? ((X8 + 9u) & 1023u)      // outer neighbor of E
                     : ((X8 + 1022u) & 1023u);

  uint32_t eA_up = in[base + (yp1 << 10) + xe];
  uint32_t eA_dn = in[base + (ym1 << 10) + xe];
  uint32_t eOwn  = in[base + (y << 10) + yeA];
  uint32_t Eself = in[base + (y << 10) + xe];
  uint32_t Eout  = in[base + (y << 10) + xo];

  uint32_t cro = (b << 19) | (y   << 9) | (X8 >> 1);
  uint32_t crm = (b << 19) | (ym1 << 9) | (X8 >> 1);
  uint32_t crp = (b << 19) | (yp1 << 9) | (X8 >> 1);
  uint32_t cwA0 = *(const uint32_t*)(codeA + cro);
  uint32_t cwAm = *(const uint32_t*)(codeA + crm);
  uint32_t cwAp = *(const uint32_t*)(codeA + crp);
  uint32_t bkE  = codeA[(b << 19) | (y << 9) | (xe >> 1)];
  uint32_t cwB  = *(const uint32_t*)(codeB + cro);

  uint32_t nwA0[4], nwAp[4], nwAm[4];
  upd_row(p0,  pp1, pm1, eOwn,  c_a, cwA0, nwA0);   // ta row y
  upd_row(pp1, pp2, p0,  eA_up, c_b, cwAp, nwAp);   // ta row y+1
  upd_row(pm1, p0,  pm2, eA_dn, c_b, cwAm, nwAm);   // ta row y-1

  // ta boundary byte E at (y, xe): parity c_a active.
  uint32_t Ert, Elf;
  if (c_b) { Elf = BY(p0, 7); Ert = Eout; }         // xe = X8+8
  else     { Ert = BY(p0, 0); Elf = Eout; }         // xe = X8-1
  uint32_t E1 = upd1(Eself, eA_up, eA_dn, Ert, Elf, bkE);

  // tb on row y: actives x = X8+2k+c_b; neighbors are post-ta values.
  uint32_t nwB[4];
#pragma unroll
  for (int k = 0; k < 4; k++) {
    uint32_t self = c_b ? BY(p0, 2 * k + 1) : BY(p0, 2 * k);  // ta-passive
    uint32_t lf, rt;
    if (c_b) { lf = nwA0[k];                 rt = (k == 3) ? E1 : nwA0[k + 1]; }
    else     { lf = (k == 0) ? E1 : nwA0[k - 1]; rt = nwA0[k]; }
    nwB[k] = upd1(self, nwAp[k], nwAm[k], rt, lf, (cwB >> (8 * k)) & 0xffu);
  }

  if (!LAST) {
    uint64_t A = 0;
#pragma unroll
    for (int k = 0; k < 4; k++) {
      A |= (uint64_t)nwA0[k] << (8 * (2 * k + (int)c_a));
      A |= (uint64_t)nwB[k]  << (8 * (2 * k + (int)c_b));
    }
    *(uint64_t*)(outids + base + (y << 10) + X8) = A;
  } else {
    float f[8];
#pragma unroll
    for (int j = 0; j < 8; j++) {
      uint32_t bj = (((uint32_t)j & 1u) == c_a) ? nwA0[j >> 1] : nwB[j >> 1];
      f[j] = (float)bj;
    }
    float4 f0 = {f[0], f[1], f[2], f[3]};
    float4 f1 = {f[4], f[5], f[6], f[7]};
    float* op = out + ((size_t)b << 23) + (y << 10) + X8;
    *(float4*)op       = f0;
    *(float4*)(op + 4) = f1;
  }
}

// ----------------------------------------------- fallback (small-ws) kernels
__device__ __forceinline__ void metro_one(uint32_t u, uint32_t sub,
                                          uint8_t* __restrict__ ids,
                                          const float* __restrict__ dHNN,
                                          uint32_t dk0, uint32_t dk1,
                                          uint32_t uk0, uint32_t uk1) {
  uint32_t b = u >> 19;
  uint32_t r = u & 524287u;
  uint32_t y = r >> 9;
  uint32_t i = r & 511u;
  uint32_t x = (i << 1) | ((y + sub) & 1u);
  uint32_t p = (b << 20) | (y << 10) | x;
  float4 dnn = ((const float4*)dHNN)[sub * NHu + u];
  uint32_t d0, d1, u0, u1;
  tf2x32(dk0, dk1, 0u, p, d0, d1);
  uint32_t db = d0 ^ d1;
  tf2x32(uk0, uk1, 0u, p, u0, u1);
  uint32_t ub = u0 ^ u1;
  int   dir = (int)(db & 3u);
  float uu  = __fsub_rn(__uint_as_float((ub >> 9) | 0x3F800000u), 1.0f);
  uint32_t yN = (y + 1) & 1023u, yP = (y - 1) & 1023u;
  uint32_t xN = (x + 1) & 1023u, xP = (x - 1) & 1023u;
  uint32_t base = b << 20;
  uint32_t cc = ids[p];
  uint32_t n0 = ids[base + (yN << 10) + x];
  uint32_t n1 = ids[base + (yP << 10) + x];
  uint32_t n2 = ids[base + (y << 10) + xN];
  uint32_t n3 = ids[base + (y << 10) + xP];
  uint32_t s  = (dir == 0) ? n0 : (dir == 1) ? n1 : (dir == 2) ? n2 : n3;
  float dH_nn = (dir == 0) ? dnn.x : (dir == 1) ? dnn.y : (dir == 2) ? dnn.z : dnn.w;
  int dadh = ((int)(n0 != s) + (int)(n1 != s) + (int)(n2 != s) + (int)(n3 != s))
           - ((int)(n0 != cc) + (int)(n1 != cc) + (int)(n2 != cc) + (int)(n3 != cc));
  float dH = __fadd_rn((float)dadh, dH_nn);
  if (uu < xla_expf(-dH)) ids[p] = (uint8_t)s;
}

__global__ __launch_bounds__(256) void prep4_fb(const float* __restrict__ X,
                                                const float* __restrict__ W,
                                                const float* __restrict__ Bb,
                                                float* __restrict__ dHNN,
                                                uint8_t* __restrict__ ids) {
  int tid = blockIdx.x * 256 + threadIdx.x;
  int e   = tid << 2;
  int b   = e >> 20;
  int yx  = e & (HW - 1);
  int y   = yx >> 10;
  int x0  = yx & 1023;
  int q4  = yx >> 2;
  const float4* xb = (const float4*)(X + ((size_t)b << 23));
  float4 xc[8];
#pragma unroll
  for (int c = 0; c < 8; c++) xc[c] = xb[(c << 18) + q4];
#pragma unroll
  for (int j = 0; j < 4; j++) {
    float4 r;
#pragma unroll
    for (int o = 0; o < 4; o++) {
      float acc = 0.0f;
#pragma unroll
      for (int c = 0; c < 8; c++)
        acc = __fadd_rn(acc, __fmul_rn(((const float*)&xc[c])[j], W[o * 8 + c]));
      ((float*)&r)[o] = __fadd_rn(acc, Bb[o]);
    }
    int xj = x0 + j;
    ((float4*)dHNN)[((xj + y) & 1) * NHu + (uint32_t)((b << 19) | (y << 9) | (xj >> 1))] = r;
  }
  uchar4 v;
  v.x = (uint8_t)(int)xc[0].x; v.y = (uint8_t)(int)xc[0].y;
  v.z = (uint8_t)(int)xc[0].z; v.w = (uint8_t)(int)xc[0].w;
  *(uchar4*)(ids + e) = v;
}

__global__ __launch_bounds__(256) void half_step_fb(uint8_t* __restrict__ ids,
                                                    const float* __restrict__ dHNN,
                                                    uint32_t dk0, uint32_t dk1,
                                                    uint32_t uk0, uint32_t uk1,
                                                    int sub) {
  uint32_t u = blockIdx.x * 256u + threadIdx.x;
  metro_one(u, (uint32_t)sub, ids, dHNN, dk0, dk1, uk0, uk1);
}

__global__ __launch_bounds__(256) void finalize_full_fb(const float* __restrict__ X,
                                                        const uint8_t* __restrict__ ids,
                                                        float* __restrict__ out) {
  int t = blockIdx.x * 256 + threadIdx.x;
  int e = t << 2;
  int c = (e >> 20) & 7;
  float4 r;
  if (c == 0) {
    int b  = e >> 23;
    int yx = e & (HW - 1);
    uchar4 v = *(const uchar4*)(ids + ((size_t)b << 20) + yx);
    r.x = (float)v.x; r.y = (float)v.y; r.z = (float)v.z; r.w = (float)v.w;
  } else {
    r = ((const float4*)X)[t];
  }
  ((float4*)out)[t] = r;
}

// --------------------------------------------------------------------- host
extern "C" void kernel_launch(void* const* d_in, const int* in_sizes, int n_in,
                              void* d_out, int out_size, void* d_ws, size_t ws_size,
                              hipStream_t stream) {
  const float* X  = (const float*)d_in[0];
  const float* W  = (const float*)d_in[1];
  const float* Bb = (const float*)d_in[2];
  float* out = (float*)d_out;

  const size_t CODE_BYTES = (size_t)NHu * 8u;    // 33.5 MB (8 planes)
  const size_t IDS_BYTES  = (size_t)BHWu;        // 8.4 MB each

  // Threefry key chain (partitionable stream; verified rounds 2-11).
  uint32_t bk0 = 0u, bk1 = 42u;
  uint32_t keys[8][2];
  for (uint32_t t = 0; t < 8; t++)
    tf2x32(bk0, bk1, 0u, t, keys[t][0], keys[t][1]);
  uint32_t K[8][4];
  KeysK KK;
  for (int t = 0; t < 8; t++) {
    uint32_t k1a, k1b;
    tf2x32(keys[t][0], keys[t][1], 0u, 0u, k1a, k1b);         // k1 (randint arg)
    tf2x32(keys[t][0], keys[t][1], 0u, 1u, K[t][2], K[t][3]); // k2 -> ukey
    tf2x32(k1a, k1b, 0u, 1u, K[t][0], K[t][1]);               // randint kk2 -> dkey
    KK.d[t][0] = K[t][0]; KK.d[t][1] = K[t][1];
    KK.u[t][0] = K[t][2]; KK.u[t][1] = K[t][3];
  }

  bool ws_ok = ws_size >= CODE_BYTES + 2 * IDS_BYTES;
  if (ws_ok) {
    uint8_t* code = (uint8_t*)d_ws;
    uint8_t* ids0 = (uint8_t*)d_ws + CODE_BYTES;
    uint8_t* ids1 = ids0 + IDS_BYTES;

    prep_fused4<<<11776, 256, 0, stream>>>(X, W, Bb, code, ids0, out, KK);
    step2_d<0><<<4096, 256, 0, stream>>>(ids0, ids1,
        code + 0 * (size_t)NHu, code + 1 * (size_t)NHu, out);
    step2_d<0><<<4096, 256, 0, stream>>>(ids1, ids0,
        code + 2 * (size_t)NHu, code + 3 * (size_t)NHu, out);
    step2_d<0><<<4096, 256, 0, stream>>>(ids0, ids1,
        code + 4 * (size_t)NHu, code + 5 * (size_t)NHu, out);
    step2_d<1><<<4096, 256, 0, stream>>>(ids1, ids0,
        code + 6 * (size_t)NHu, code + 7 * (size_t)NHu, out);
  } else {
    float*   dHNN = out;                 // dHNN lives in out; ids in ws
    uint8_t* ids  = (uint8_t*)d_ws;
    prep4_fb<<<8192, 256, 0, stream>>>(X, W, Bb, dHNN, ids);
    for (int t = 0; t < 8; t++)
      half_step_fb<<<16384, 256, 0, stream>>>(ids, dHNN,
          K[t][0], K[t][1], K[t][2], K[t][3], t & 1);
    finalize_full_fb<<<65536, 256, 0, stream>>>(X, ids, out);
  }
  (void)in_sizes; (void)n_in; (void)out_size;
}

// Round 13
// 221.798 us; speedup vs baseline: 1.2976x; 1.0328x over previous
//
#include <hip/hip_runtime.h>
#include <stdint.h>

// ============================================================================
// CPM layer, bit-exact JAX reproduction. B=8, C=8, H=W=1024.
// Round 13: copy de-dilution — the ch1-7 pass-through moves from dedicated
// copy BLOCKS (7/23 of the grid, idle VALU) into an epilogue slice in EVERY
// compute block (7 float4/thread, 4+3 batched). VMEM issues from the same
// waves; VALU slots of all 256 CUs now do cipher work.
// step2_d chain (round-12 verified) unchanged.
// RNG / dot / exp / certainty-band decision code bit-identical to rounds 2-12.
// ============================================================================

#define HW    1048576    // 1024*1024
#define BHWu  8388608u   // 8*HW
#define NHu   4194304u   // BHW/2 = code plane bytes

struct KeysK { uint32_t d[8][2]; uint32_t u[8][2]; };

// ---------------------------------------------------------------------- RNG
__device__ __host__ __forceinline__ void tf2x32(uint32_t k0, uint32_t k1,
                                                uint32_t x0, uint32_t x1,
                                                uint32_t& o0, uint32_t& o1) {
  uint32_t k2 = k0 ^ k1 ^ 0x1BD11BDAu;
  x0 += k0; x1 += k1;
#define RDD(r) { x0 += x1; x1 = ((x1 << (r)) | (x1 >> (32 - (r)))) ^ x0; }
  RDD(13) RDD(15) RDD(26) RDD(6)
  x0 += k1; x1 += k2 + 1u;
  RDD(17) RDD(29) RDD(16) RDD(24)
  x0 += k2; x1 += k0 + 2u;
  RDD(13) RDD(15) RDD(26) RDD(6)
  x0 += k0; x1 += k1 + 3u;
  RDD(17) RDD(29) RDD(16) RDD(24)
  x0 += k1; x1 += k2 + 4u;
  RDD(13) RDD(15) RDD(26) RDD(6)
  x0 += k2; x1 += k0 + 5u;
#undef RDD
  o0 = x0; o1 = x1;
}

// ------------------------------------------------- XLA-CPU Cephes expf clone
__device__ __forceinline__ float xla_expf(float input) {
  float x  = fmaxf(fminf(input, 88.3762626647950f), -88.3762626647949f);
  float fx = floorf(fmaf(x, 1.44269504088896341f, 0.5f));
  float tmp = __fmul_rn(0.693359375f, fx);
  float z   = __fmul_rn(-2.12194440e-4f, fx);
  x = __fsub_rn(x, tmp);
  x = __fsub_rn(x, z);
  z = __fmul_rn(x, x);
  float y = fmaf(x, 1.9875691500e-4f, 1.3981999507e-3f);
  y = fmaf(y, x, 8.3334519073e-3f);
  y = fmaf(y, x, 4.1665795894e-2f);
  y = fmaf(y, x, 1.6666665459e-1f);
  y = fmaf(y, x, 5.0000001201e-1f);
  y = fmaf(y, z, x);
  y = __fadd_rn(y, 1.0f);
  int n = (int)fx;
  float p2n = __int_as_float((n + 127) << 23);
  return fmaxf(__fmul_rn(y, p2n), input);
}

#define BY(v, i) ((uint32_t)(((v) >> ((i) * 8)) & 0xffu))
#define ACC_D(dd) (u < xla_expf(-__fadd_rn((float)(dd), v)))

// ------------------------------------------------------------------- kernels
// prep_all: 8192 blocks, one row each, 4 px/thread. Compute identical to
// round-11/12 prep_fused4's compute role; epilogue copies 1792 float4 of
// the ch1-7 pass-through per block (issued on the memory pipe, VALU-hidden).
__global__ __launch_bounds__(256) void prep_all(const float* __restrict__ X,
                                                const float* __restrict__ W,
                                                const float* __restrict__ Bb,
                                                uint8_t* __restrict__ code,
                                                uint8_t* __restrict__ ids,
                                                float* __restrict__ out,
                                                KeysK K) {
  const uint32_t tid = threadIdx.x;
  const uint32_t row = blockIdx.x;            // 0..8191
  const uint32_t b = row >> 10, y = row & 1023u;
  const uint32_t ylsb = y & 1u;
  const uint32_t x0 = 4u * tid;

  const float4* xb = (const float4*)(X + ((size_t)b << 23));
  const uint32_t fq = (y << 8) + tid;

  float acc[4][4];
  float c0[4];
#pragma unroll
  for (int c = 0; c < 8; c++) {
    float4 a = xb[((uint32_t)c << 18) + fq];
    float xs[4] = {a.x, a.y, a.z, a.w};
    if (c == 0) {
#pragma unroll
      for (int px = 0; px < 4; px++) c0[px] = xs[px];
    }
#pragma unroll
    for (int px = 0; px < 4; px++)
#pragma unroll
      for (int o = 0; o < 4; o++) {
        float m = __fmul_rn(xs[px], W[o * 8 + c]);
        acc[px][o] = (c == 0) ? __fadd_rn(0.0f, m) : __fadd_rn(acc[px][o], m);
      }
  }
#pragma unroll
  for (int px = 0; px < 4; px++)
#pragma unroll
    for (int o = 0; o < 4; o++) acc[px][o] = __fadd_rn(acc[px][o], Bb[o]);

  {  // ids: 4 bytes packed
    uchar4 v;
    v.x = (uint8_t)(int)c0[0]; v.y = (uint8_t)(int)c0[1];
    v.z = (uint8_t)(int)c0[2]; v.w = (uint8_t)(int)c0[3];
    *(uchar4*)(ids + (b << 20) + (y << 10) + x0) = v;
  }

  const uint32_t pbase   = (b << 20) | (y << 10);
  const uint32_t codeoff = (b << 19) | (y << 9) | (x0 >> 1);
#pragma unroll
  for (int js = 0; js < 4; js++) {
#pragma unroll
    for (int pb = 0; pb < 2; pb++) {
      uint32_t s0 = ylsb ^ (uint32_t)pb;      // step t = 2*js + s0
      uint32_t dka = s0 ? K.d[2 * js + 1][0] : K.d[2 * js][0];
      uint32_t dkb = s0 ? K.d[2 * js + 1][1] : K.d[2 * js][1];
      uint32_t uka = s0 ? K.u[2 * js + 1][0] : K.u[2 * js][0];
      uint32_t ukb = s0 ? K.u[2 * js + 1][1] : K.u[2 * js][1];
      uint32_t cword = 0;
#pragma unroll
      for (int k = 0; k < 2; k++) {
        int px = 2 * k + pb;
        uint32_t p = pbase | (x0 + (uint32_t)px);
        uint32_t o0, o1, q0, q1;
        tf2x32(dka, dkb, 0u, p, o0, o1);
        uint32_t dir = (o0 ^ o1) & 3u;
        tf2x32(uka, ukb, 0u, p, q0, q1);
        uint32_t ub = (q0 ^ q1) >> 9;
        float u = __fsub_rn(__uint_as_float(ub | 0x3F800000u), 1.0f);
        float v = (dir == 0) ? acc[px][0] : (dir == 1) ? acc[px][1]
                : (dir == 2) ? acc[px][2] : acc[px][3];
        int dstar;
        if (ub == 0u) {                       // u == 0: always accept
          dstar = 4;
        } else {
          float l2  = __log2f(u);             // v_log_f32
          float tau = fmaf(-0.693147180559945f, l2, -v);
          float gf  = floorf(tau);
          float fr  = tau - gf;
          int   gi  = (int)fmaxf(fminf(gf, 6.0f), -7.0f);
          dstar = gi;
          if (fr < 1e-4f)        dstar = ACC_D(gi)     ? gi     : gi - 1;
          else if (fr > 0.9999f) dstar = ACC_D(gi + 1) ? gi + 1 : gi;
        }
        dstar = dstar < -5 ? -5 : (dstar > 4 ? 4 : dstar);
        cword |= (uint32_t)((uint32_t)(dstar + 5) | (dir << 4)) << (8 * k);
      }
      uint32_t t = 2u * (uint32_t)js + s0;
      *(uint16_t*)(code + (size_t)t * NHu + codeoff) = (uint16_t)cword;
    }
  }

  // ---- epilogue: ch1-7 pass-through slice, 1792 f4/block = 7/thread (4+3)
  {
    const float4* X4 = (const float4*)X;
    float4*       O4 = (float4*)out;
    const uint32_t fb = blockIdx.x * 1792u + tid;
    size_t idxs[4]; float4 v[4];
#pragma unroll
    for (int j = 0; j < 4; j++) {
      uint32_t F = fb + 256u * j;
      uint32_t b2 = F / 1835008u;
      idxs[j] = ((size_t)b2 << 21) + 262144u + (F - b2 * 1835008u);
      v[j] = X4[idxs[j]];
    }
#pragma unroll
    for (int j = 0; j < 4; j++) O4[idxs[j]] = v[j];
#pragma unroll
    for (int j = 4; j < 7; j++) {
      uint32_t F = fb + 256u * j;
      uint32_t b2 = F / 1835008u;
      size_t idx = ((size_t)b2 << 21) + 262144u + (F - b2 * 1835008u);
      O4[idx] = X4[idx];
    }
  }
}

// --------------------------------------------------- fused double-step logic
__device__ __forceinline__ uint32_t upd1(uint32_t self, uint32_t n0, uint32_t n1,
                                         uint32_t rt, uint32_t lf, uint32_t bk) {
  uint32_t dir = (bk >> 4) & 3u;
  uint32_t ds5 = bk & 15u;
  uint32_t s = (dir == 0) ? n0 : (dir == 1) ? n1 : (dir == 2) ? rt : lf;
  int dadh = ((int)(n0 != s) + (int)(n1 != s) + (int)(rt != s) + (int)(lf != s))
           - ((int)(n0 != self) + (int)(n1 != self) + (int)(rt != self) + (int)(lf != self));
  return ((uint32_t)(dadh + 5) <= ds5) ? s : self;
}

__device__ __forceinline__ void upd_row(uint64_t mid, uint64_t up, uint64_t dn,
                                        uint32_t e, uint32_t c, uint32_t cw,
                                        uint32_t nw[4]) {
#pragma unroll
  for (int k = 0; k < 4; k++) {
    uint32_t self  = c ? BY(mid, 2 * k + 1) : BY(mid, 2 * k);
    uint32_t left  = c ? BY(mid, 2 * k)
                       : ((k == 0) ? e : BY(mid, 2 * k - 1));
    uint32_t right = c ? ((k == 3) ? e : BY(mid, 2 * k + 2))
                       : BY(mid, 2 * k + 1);
    uint32_t n0 = c ? BY(up, 2 * k + 1) : BY(up, 2 * k);   // roll(-1,0): y+1
    uint32_t n1 = c ? BY(dn, 2 * k + 1) : BY(dn, 2 * k);   // roll(+1,0): y-1
    nw[k] = upd1(self, n0, n1, right, left, (cw >> (8 * k)) & 0xffu);
  }
}

// step2_d: steps ta (sub=0) and ta+1 (sub=1) fused; ping-pong buffers.
template <int LAST>
__global__ __launch_bounds__(256) void step2_d(const uint8_t* __restrict__ in,
                                               uint8_t* __restrict__ outids,
                                               const uint8_t* __restrict__ codeA,
                                               const uint8_t* __restrict__ codeB,
                                               float* __restrict__ out) {
  uint32_t n  = blockIdx.x * 256u + (uint32_t)threadIdx.x;   // 0 .. 2^20-1
  uint32_t b  = n >> 17;
  uint32_t y  = (n >> 7) & 1023u;
  uint32_t X8 = (n & 127u) << 3;
  uint32_t base = b << 20;
  uint32_t ym2 = (y - 2u) & 1023u, ym1 = (y - 1u) & 1023u;
  uint32_t yp1 = (y + 1u) & 1023u, yp2 = (y + 2u) & 1023u;
  uint32_t c_a = y & 1u;          // ta (sub=0) active x-parity in row y
  uint32_t c_b = 1u - c_a;        // tb (sub=1) active x-parity in row y

  uint64_t pm2 = *(const uint64_t*)(in + base + (ym2 << 10) + X8);
  uint64_t pm1 = *(const uint64_t*)(in + base + (ym1 << 10) + X8);
  uint64_t p0  = *(const uint64_t*)(in + base + (y   << 10) + X8);
  uint64_t pp1 = *(const uint64_t*)(in + base + (yp1 << 10) + X8);
  uint64_t pp2 = *(const uint64_t*)(in + base + (yp2 << 10) + X8);

  uint32_t exL = (X8 + 1023u) & 1023u;          // X8-1
  uint32_t exR = (X8 + 8u) & 1023u;             // X8+8
  uint32_t xe  = c_b ? exR : exL;               // tb boundary / rows y±1 ta edge
  uint32_t yeA = c_a ? exR : exL;               // row y ta edge (opposite side)
  uint32_t xo  = c_b ? ((X8 + 9u) & 1023u)
                     : ((X8 + 1022u) & 1023u);

  uint32_t eA_up = in[base + (yp1 << 10) + xe];
  uint32_t eA_dn = in[base + (ym1 << 10) + xe];
  uint32_t eOwn  = in[base + (y << 10) + yeA];
  uint32_t Eself = in[base + (y << 10) + xe];
  uint32_t Eout  = in[base + (y << 10) + xo];

  uint32_t cro = (b << 19) | (y   << 9) | (X8 >> 1);
  uint32_t crm = (b << 19) | (ym1 << 9) | (X8 >> 1);
  uint32_t crp = (b << 19) | (yp1 << 9) | (X8 >> 1);
  uint32_t cwA0 = *(const uint32_t*)(codeA + cro);
  uint32_t cwAm = *(const uint32_t*)(codeA + crm);
  uint32_t cwAp = *(const uint32_t*)(codeA + crp);
  uint32_t bkE  = codeA[(b << 19) | (y << 9) | (xe >> 1)];
  uint32_t cwB  = *(const uint32_t*)(codeB + cro);

  uint32_t nwA0[4], nwAp[4], nwAm[4];
  upd_row(p0,  pp1, pm1, eOwn,  c_a, cwA0, nwA0);   // ta row y
  upd_row(pp1, pp2, p0,  eA_up, c_b, cwAp, nwAp);   // ta row y+1
  upd_row(pm1, p0,  pm2, eA_dn, c_b, cwAm, nwAm);   // ta row y-1

  uint32_t Ert, Elf;
  if (c_b) { Elf = BY(p0, 7); Ert = Eout; }         // xe = X8+8
  else     { Ert = BY(p0, 0); Elf = Eout; }         // xe = X8-1
  uint32_t E1 = upd1(Eself, eA_up, eA_dn, Ert, Elf, bkE);

  uint32_t nwB[4];
#pragma unroll
  for (int k = 0; k < 4; k++) {
    uint32_t self = c_b ? BY(p0, 2 * k + 1) : BY(p0, 2 * k);
    uint32_t lf, rt;
    if (c_b) { lf = nwA0[k];                 rt = (k == 3) ? E1 : nwA0[k + 1]; }
    else     { lf = (k == 0) ? E1 : nwA0[k - 1]; rt = nwA0[k]; }
    nwB[k] = upd1(self, nwAp[k], nwAm[k], rt, lf, (cwB >> (8 * k)) & 0xffu);
  }

  if (!LAST) {
    uint64_t A = 0;
#pragma unroll
    for (int k = 0; k < 4; k++) {
      A |= (uint64_t)nwA0[k] << (8 * (2 * k + (int)c_a));
      A |= (uint64_t)nwB[k]  << (8 * (2 * k + (int)c_b));
    }
    *(uint64_t*)(outids + base + (y << 10) + X8) = A;
  } else {
    float f[8];
#pragma unroll
    for (int j = 0; j < 8; j++) {
      uint32_t bj = (((uint32_t)j & 1u) == c_a) ? nwA0[j >> 1] : nwB[j >> 1];
      f[j] = (float)bj;
    }
    float4 f0 = {f[0], f[1], f[2], f[3]};
    float4 f1 = {f[4], f[5], f[6], f[7]};
    float* op = out + ((size_t)b << 23) + (y << 10) + X8;
    *(float4*)op       = f0;
    *(float4*)(op + 4) = f1;
  }
}

// ----------------------------------------------- fallback (small-ws) kernels
__device__ __forceinline__ void metro_one(uint32_t u, uint32_t sub,
                                          uint8_t* __restrict__ ids,
                                          const float* __restrict__ dHNN,
                                          uint32_t dk0, uint32_t dk1,
                                          uint32_t uk0, uint32_t uk1) {
  uint32_t b = u >> 19;
  uint32_t r = u & 524287u;
  uint32_t y = r >> 9;
  uint32_t i = r & 511u;
  uint32_t x = (i << 1) | ((y + sub) & 1u);
  uint32_t p = (b << 20) | (y << 10) | x;
  float4 dnn = ((const float4*)dHNN)[sub * NHu + u];
  uint32_t d0, d1, u0, u1;
  tf2x32(dk0, dk1, 0u, p, d0, d1);
  uint32_t db = d0 ^ d1;
  tf2x32(uk0, uk1, 0u, p, u0, u1);
  uint32_t ub = u0 ^ u1;
  int   dir = (int)(db & 3u);
  float uu  = __fsub_rn(__uint_as_float((ub >> 9) | 0x3F800000u), 1.0f);
  uint32_t yN = (y + 1) & 1023u, yP = (y - 1) & 1023u;
  uint32_t xN = (x + 1) & 1023u, xP = (x - 1) & 1023u;
  uint32_t base = b << 20;
  uint32_t cc = ids[p];
  uint32_t n0 = ids[base + (yN << 10) + x];
  uint32_t n1 = ids[base + (yP << 10) + x];
  uint32_t n2 = ids[base + (y << 10) + xN];
  uint32_t n3 = ids[base + (y << 10) + xP];
  uint32_t s  = (dir == 0) ? n0 : (dir == 1) ? n1 : (dir == 2) ? n2 : n3;
  float dH_nn = (dir == 0) ? dnn.x : (dir == 1) ? dnn.y : (dir == 2) ? dnn.z : dnn.w;
  int dadh = ((int)(n0 != s) + (int)(n1 != s) + (int)(n2 != s) + (int)(n3 != s))
           - ((int)(n0 != cc) + (int)(n1 != cc) + (int)(n2 != cc) + (int)(n3 != cc));
  float dH = __fadd_rn((float)dadh, dH_nn);
  if (uu < xla_expf(-dH)) ids[p] = (uint8_t)s;
}

__global__ __launch_bounds__(256) void prep4_fb(const float* __restrict__ X,
                                                const float* __restrict__ W,
                                                const float* __restrict__ Bb,
                                                float* __restrict__ dHNN,
                                                uint8_t* __restrict__ ids) {
  int tid = blockIdx.x * 256 + threadIdx.x;
  int e   = tid << 2;
  int b   = e >> 20;
  int yx  = e & (HW - 1);
  int y   = yx >> 10;
  int x0  = yx & 1023;
  int q4  = yx >> 2;
  const float4* xb = (const float4*)(X + ((size_t)b << 23));
  float4 xc[8];
#pragma unroll
  for (int c = 0; c < 8; c++) xc[c] = xb[(c << 18) + q4];
#pragma unroll
  for (int j = 0; j < 4; j++) {
    float4 r;
#pragma unroll
    for (int o = 0; o < 4; o++) {
      float acc = 0.0f;
#pragma unroll
      for (int c = 0; c < 8; c++)
        acc = __fadd_rn(acc, __fmul_rn(((const float*)&xc[c])[j], W[o * 8 + c]));
      ((float*)&r)[o] = __fadd_rn(acc, Bb[o]);
    }
    int xj = x0 + j;
    ((float4*)dHNN)[((xj + y) & 1) * NHu + (uint32_t)((b << 19) | (y << 9) | (xj >> 1))] = r;
  }
  uchar4 v;
  v.x = (uint8_t)(int)xc[0].x; v.y = (uint8_t)(int)xc[0].y;
  v.z = (uint8_t)(int)xc[0].z; v.w = (uint8_t)(int)xc[0].w;
  *(uchar4*)(ids + e) = v;
}

__global__ __launch_bounds__(256) void half_step_fb(uint8_t* __restrict__ ids,
                                                    const float* __restrict__ dHNN,
                                                    uint32_t dk0, uint32_t dk1,
                                                    uint32_t uk0, uint32_t uk1,
                                                    int sub) {
  uint32_t u = blockIdx.x * 256u + threadIdx.x;
  metro_one(u, (uint32_t)sub, ids, dHNN, dk0, dk1, uk0, uk1);
}

__global__ __launch_bounds__(256) void finalize_full_fb(const float* __restrict__ X,
                                                        const uint8_t* __restrict__ ids,
                                                        float* __restrict__ out) {
  int t = blockIdx.x * 256 + threadIdx.x;
  int e = t << 2;
  int c = (e >> 20) & 7;
  float4 r;
  if (c == 0) {
    int b  = e >> 23;
    int yx = e & (HW - 1);
    uchar4 v = *(const uchar4*)(ids + ((size_t)b << 20) + yx);
    r.x = (float)v.x; r.y = (float)v.y; r.z = (float)v.z; r.w = (float)v.w;
  } else {
    r = ((const float4*)X)[t];
  }
  ((float4*)out)[t] = r;
}

// --------------------------------------------------------------------- host
extern "C" void kernel_launch(void* const* d_in, const int* in_sizes, int n_in,
                              void* d_out, int out_size, void* d_ws, size_t ws_size,
                              hipStream_t stream) {
  const float* X  = (const float*)d_in[0];
  const float* W  = (const float*)d_in[1];
  const float* Bb = (const float*)d_in[2];
  float* out = (float*)d_out;

  const size_t CODE_BYTES = (size_t)NHu * 8u;    // 33.5 MB (8 planes)
  const size_t IDS_BYTES  = (size_t)BHWu;        // 8.4 MB each

  // Threefry key chain (partitionable stream; verified rounds 2-12).
  uint32_t bk0 = 0u, bk1 = 42u;
  uint32_t keys[8][2];
  for (uint32_t t = 0; t < 8; t++)
    tf2x32(bk0, bk1, 0u, t, keys[t][0], keys[t][1]);
  uint32_t K[8][4];
  KeysK KK;
  for (int t = 0; t < 8; t++) {
    uint32_t k1a, k1b;
    tf2x32(keys[t][0], keys[t][1], 0u, 0u, k1a, k1b);         // k1 (randint arg)
    tf2x32(keys[t][0], keys[t][1], 0u, 1u, K[t][2], K[t][3]); // k2 -> ukey
    tf2x32(k1a, k1b, 0u, 1u, K[t][0], K[t][1]);               // randint kk2 -> dkey
    KK.d[t][0] = K[t][0]; KK.d[t][1] = K[t][1];
    KK.u[t][0] = K[t][2]; KK.u[t][1] = K[t][3];
  }

  bool ws_ok = ws_size >= CODE_BYTES + 2 * IDS_BYTES;
  if (ws_ok) {
    uint8_t* code = (uint8_t*)d_ws;
    uint8_t* ids0 = (uint8_t*)d_ws + CODE_BYTES;
    uint8_t* ids1 = ids0 + IDS_BYTES;

    prep_all<<<8192, 256, 0, stream>>>(X, W, Bb, code, ids0, out, KK);
    step2_d<0><<<4096, 256, 0, stream>>>(ids0, ids1,
        code + 0 * (size_t)NHu, code + 1 * (size_t)NHu, out);
    step2_d<0><<<4096, 256, 0, stream>>>(ids1, ids0,
        code + 2 * (size_t)NHu, code + 3 * (size_t)NHu, out);
    step2_d<0><<<4096, 256, 0, stream>>>(ids0, ids1,
        code + 4 * (size_t)NHu, code + 5 * (size_t)NHu, out);
    step2_d<1><<<4096, 256, 0, stream>>>(ids1, ids0,
        code + 6 * (size_t)NHu, code + 7 * (size_t)NHu, out);
  } else {
    float*   dHNN = out;                 // dHNN lives in out; ids in ws
    uint8_t* ids  = (uint8_t*)d_ws;
    prep4_fb<<<8192, 256, 0, stream>>>(X, W, Bb, dHNN, ids);
    for (int t = 0; t < 8; t++)
      half_step_fb<<<16384, 256, 0, stream>>>(ids, dHNN,
          K[t][0], K[t][1], K[t][2], K[t][3], t & 1);
    finalize_full_fb<<<65536, 256, 0, stream>>>(X, ids, out);
  }
  (void)in_sizes; (void)n_in; (void)out_size;
}

// Round 14
// 219.483 us; speedup vs baseline: 1.3113x; 1.0105x over previous
//
#include <hip/hip_runtime.h>
#include <stdint.h>

// ============================================================================
// CPM layer, bit-exact JAX reproduction. B=8, C=8, H=W=1024.
// Round 14: prep branch-overhead removal —
//   (a) ub==0 special case deleted: log2(0)=-inf -> tau=+inf -> fr=NaN path
//       already yields dstar=4 (verified case analysis; NaN-safe compares).
//   (b) the two rare-band resolves merged into ONE divergent branch
//       (gg = fr>0.5 ? gi+1 : gi; dstar = ACC_D(gg) ? gg : gg-1 — identical
//       case-by-case to the two-branch version).
// Everything else (copy epilogue, step2_d chain, RNG, dot, exp) is
// byte-identical to the PASSING round-13 kernel.
// ============================================================================

#define HW    1048576    // 1024*1024
#define BHWu  8388608u   // 8*HW
#define NHu   4194304u   // BHW/2 = code plane bytes

struct KeysK { uint32_t d[8][2]; uint32_t u[8][2]; };

// ---------------------------------------------------------------------- RNG
__device__ __host__ __forceinline__ void tf2x32(uint32_t k0, uint32_t k1,
                                                uint32_t x0, uint32_t x1,
                                                uint32_t& o0, uint32_t& o1) {
  uint32_t k2 = k0 ^ k1 ^ 0x1BD11BDAu;
  x0 += k0; x1 += k1;
#define RDD(r) { x0 += x1; x1 = ((x1 << (r)) | (x1 >> (32 - (r)))) ^ x0; }
  RDD(13) RDD(15) RDD(26) RDD(6)
  x0 += k1; x1 += k2 + 1u;
  RDD(17) RDD(29) RDD(16) RDD(24)
  x0 += k2; x1 += k0 + 2u;
  RDD(13) RDD(15) RDD(26) RDD(6)
  x0 += k0; x1 += k1 + 3u;
  RDD(17) RDD(29) RDD(16) RDD(24)
  x0 += k1; x1 += k2 + 4u;
  RDD(13) RDD(15) RDD(26) RDD(6)
  x0 += k2; x1 += k0 + 5u;
#undef RDD
  o0 = x0; o1 = x1;
}

// ------------------------------------------------- XLA-CPU Cephes expf clone
__device__ __forceinline__ float xla_expf(float input) {
  float x  = fmaxf(fminf(input, 88.3762626647950f), -88.3762626647949f);
  float fx = floorf(fmaf(x, 1.44269504088896341f, 0.5f));
  float tmp = __fmul_rn(0.693359375f, fx);
  float z   = __fmul_rn(-2.12194440e-4f, fx);
  x = __fsub_rn(x, tmp);
  x = __fsub_rn(x, z);
  z = __fmul_rn(x, x);
  float y = fmaf(x, 1.9875691500e-4f, 1.3981999507e-3f);
  y = fmaf(y, x, 8.3334519073e-3f);
  y = fmaf(y, x, 4.1665795894e-2f);
  y = fmaf(y, x, 1.6666665459e-1f);
  y = fmaf(y, x, 5.0000001201e-1f);
  y = fmaf(y, z, x);
  y = __fadd_rn(y, 1.0f);
  int n = (int)fx;
  float p2n = __int_as_float((n + 127) << 23);
  return fmaxf(__fmul_rn(y, p2n), input);
}

#define BY(v, i) ((uint32_t)(((v) >> ((i) * 8)) & 0xffu))
#define ACC_D(dd) (u < xla_expf(-__fadd_rn((float)(dd), v)))

// ------------------------------------------------------------------- kernels
// prep_all: 8192 blocks, one row each, 4 px/thread; ch1-7 copy epilogue.
__global__ __launch_bounds__(256) void prep_all(const float* __restrict__ X,
                                                const float* __restrict__ W,
                                                const float* __restrict__ Bb,
                                                uint8_t* __restrict__ code,
                                                uint8_t* __restrict__ ids,
                                                float* __restrict__ out,
                                                KeysK K) {
  const uint32_t tid = threadIdx.x;
  const uint32_t row = blockIdx.x;            // 0..8191
  const uint32_t b = row >> 10, y = row & 1023u;
  const uint32_t ylsb = y & 1u;
  const uint32_t x0 = 4u * tid;

  const float4* xb = (const float4*)(X + ((size_t)b << 23));
  const uint32_t fq = (y << 8) + tid;

  float acc[4][4];
  float c0[4];
#pragma unroll
  for (int c = 0; c < 8; c++) {
    float4 a = xb[((uint32_t)c << 18) + fq];
    float xs[4] = {a.x, a.y, a.z, a.w};
    if (c == 0) {
#pragma unroll
      for (int px = 0; px < 4; px++) c0[px] = xs[px];
    }
#pragma unroll
    for (int px = 0; px < 4; px++)
#pragma unroll
      for (int o = 0; o < 4; o++) {
        float m = __fmul_rn(xs[px], W[o * 8 + c]);
        acc[px][o] = (c == 0) ? __fadd_rn(0.0f, m) : __fadd_rn(acc[px][o], m);
      }
  }
#pragma unroll
  for (int px = 0; px < 4; px++)
#pragma unroll
    for (int o = 0; o < 4; o++) acc[px][o] = __fadd_rn(acc[px][o], Bb[o]);

  {  // ids: 4 bytes packed
    uchar4 v;
    v.x = (uint8_t)(int)c0[0]; v.y = (uint8_t)(int)c0[1];
    v.z = (uint8_t)(int)c0[2]; v.w = (uint8_t)(int)c0[3];
    *(uchar4*)(ids + (b << 20) + (y << 10) + x0) = v;
  }

  const uint32_t pbase   = (b << 20) | (y << 10);
  const uint32_t codeoff = (b << 19) | (y << 9) | (x0 >> 1);
#pragma unroll
  for (int js = 0; js < 4; js++) {
#pragma unroll
    for (int pb = 0; pb < 2; pb++) {
      uint32_t s0 = ylsb ^ (uint32_t)pb;      // step t = 2*js + s0
      uint32_t dka = s0 ? K.d[2 * js + 1][0] : K.d[2 * js][0];
      uint32_t dkb = s0 ? K.d[2 * js + 1][1] : K.d[2 * js][1];
      uint32_t uka = s0 ? K.u[2 * js + 1][0] : K.u[2 * js][0];
      uint32_t ukb = s0 ? K.u[2 * js + 1][1] : K.u[2 * js][1];
      uint32_t cword = 0;
#pragma unroll
      for (int k = 0; k < 2; k++) {
        int px = 2 * k + pb;
        uint32_t p = pbase | (x0 + (uint32_t)px);
        uint32_t o0, o1, q0, q1;
        tf2x32(dka, dkb, 0u, p, o0, o1);
        uint32_t dir = (o0 ^ o1) & 3u;
        tf2x32(uka, ukb, 0u, p, q0, q1);
        uint32_t ub = (q0 ^ q1) >> 9;
        float u = __fsub_rn(__uint_as_float(ub | 0x3F800000u), 1.0f);
        float v = (dir == 0) ? acc[px][0] : (dir == 1) ? acc[px][1]
                : (dir == 2) ? acc[px][2] : acc[px][3];
        // tau = -v - ln(u). u==0: log2->-inf, tau=+inf, fr=NaN -> both rare
        // tests false, gi=6 -> dstar clamps to 4 ("always accept"). Exact.
        float l2  = __log2f(u);               // v_log_f32
        float tau = fmaf(-0.693147180559945f, l2, -v);
        float gf  = floorf(tau);
        float fr  = tau - gf;
        int   gi  = (int)fmaxf(fminf(gf, 6.0f), -7.0f);
        int dstar = gi;
        if (fr < 1e-4f || fr > 0.9999f) {     // rare (~0.02%), NaN-safe
          int gg = (fr > 0.5f) ? gi + 1 : gi;
          dstar = ACC_D(gg) ? gg : gg - 1;    // one exact Cephes resolve
        }
        dstar = dstar < -5 ? -5 : (dstar > 4 ? 4 : dstar);
        cword |= (uint32_t)((uint32_t)(dstar + 5) | (dir << 4)) << (8 * k);
      }
      uint32_t t = 2u * (uint32_t)js + s0;
      *(uint16_t*)(code + (size_t)t * NHu + codeoff) = (uint16_t)cword;
    }
  }

  // ---- epilogue: ch1-7 pass-through slice, 1792 f4/block = 7/thread (4+3)
  {
    const float4* X4 = (const float4*)X;
    float4*       O4 = (float4*)out;
    const uint32_t fb = blockIdx.x * 1792u + tid;
    size_t idxs[4]; float4 v[4];
#pragma unroll
    for (int j = 0; j < 4; j++) {
      uint32_t F = fb + 256u * j;
      uint32_t b2 = F / 1835008u;
      idxs[j] = ((size_t)b2 << 21) + 262144u + (F - b2 * 1835008u);
      v[j] = X4[idxs[j]];
    }
#pragma unroll
    for (int j = 0; j < 4; j++) O4[idxs[j]] = v[j];
#pragma unroll
    for (int j = 4; j < 7; j++) {
      uint32_t F = fb + 256u * j;
      uint32_t b2 = F / 1835008u;
      size_t idx = ((size_t)b2 << 21) + 262144u + (F - b2 * 1835008u);
      O4[idx] = X4[idx];
    }
  }
}

// --------------------------------------------------- fused double-step logic
__device__ __forceinline__ uint32_t upd1(uint32_t self, uint32_t n0, uint32_t n1,
                                         uint32_t rt, uint32_t lf, uint32_t bk) {
  uint32_t dir = (bk >> 4) & 3u;
  uint32_t ds5 = bk & 15u;
  uint32_t s = (dir == 0) ? n0 : (dir == 1) ? n1 : (dir == 2) ? rt : lf;
  int dadh = ((int)(n0 != s) + (int)(n1 != s) + (int)(rt != s) + (int)(lf != s))
           - ((int)(n0 != self) + (int)(n1 != self) + (int)(rt != self) + (int)(lf != self));
  return ((uint32_t)(dadh + 5) <= ds5) ? s : self;
}

__device__ __forceinline__ void upd_row(uint64_t mid, uint64_t up, uint64_t dn,
                                        uint32_t e, uint32_t c, uint32_t cw,
                                        uint32_t nw[4]) {
#pragma unroll
  for (int k = 0; k < 4; k++) {
    uint32_t self  = c ? BY(mid, 2 * k + 1) : BY(mid, 2 * k);
    uint32_t left  = c ? BY(mid, 2 * k)
                       : ((k == 0) ? e : BY(mid, 2 * k - 1));
    uint32_t right = c ? ((k == 3) ? e : BY(mid, 2 * k + 2))
                       : BY(mid, 2 * k + 1);
    uint32_t n0 = c ? BY(up, 2 * k + 1) : BY(up, 2 * k);   // roll(-1,0): y+1
    uint32_t n1 = c ? BY(dn, 2 * k + 1) : BY(dn, 2 * k);   // roll(+1,0): y-1
    nw[k] = upd1(self, n0, n1, right, left, (cw >> (8 * k)) & 0xffu);
  }
}

// step2_d: steps ta (sub=0) and ta+1 (sub=1) fused; ping-pong buffers.
template <int LAST>
__global__ __launch_bounds__(256) void step2_d(const uint8_t* __restrict__ in,
                                               uint8_t* __restrict__ outids,
                                               const uint8_t* __restrict__ codeA,
                                               const uint8_t* __restrict__ codeB,
                                               float* __restrict__ out) {
  uint32_t n  = blockIdx.x * 256u + (uint32_t)threadIdx.x;   // 0 .. 2^20-1
  uint32_t b  = n >> 17;
  uint32_t y  = (n >> 7) & 1023u;
  uint32_t X8 = (n & 127u) << 3;
  uint32_t base = b << 20;
  uint32_t ym2 = (y - 2u) & 1023u, ym1 = (y - 1u) & 1023u;
  uint32_t yp1 = (y + 1u) & 1023u, yp2 = (y + 2u) & 1023u;
  uint32_t c_a = y & 1u;          // ta (sub=0) active x-parity in row y
  uint32_t c_b = 1u - c_a;        // tb (sub=1) active x-parity in row y

  uint64_t pm2 = *(const uint64_t*)(in + base + (ym2 << 10) + X8);
  uint64_t pm1 = *(const uint64_t*)(in + base + (ym1 << 10) + X8);
  uint64_t p0  = *(const uint64_t*)(in + base + (y   << 10) + X8);
  uint64_t pp1 = *(const uint64_t*)(in + base + (yp1 << 10) + X8);
  uint64_t pp2 = *(const uint64_t*)(in + base + (yp2 << 10) + X8);

  uint32_t exL = (X8 + 1023u) & 1023u;          // X8-1
  uint32_t exR = (X8 + 8u) & 1023u;             // X8+8
  uint32_t xe  = c_b ? exR : exL;               // tb boundary / rows y±1 ta edge
  uint32_t yeA = c_a ? exR : exL;               // row y ta edge (opposite side)
  uint32_t xo  = c_b ? ((X8 + 9u) & 1023u)
                     : ((X8 + 1022u) & 1023u);

  uint32_t eA_up = in[base + (yp1 << 10) + xe];
  uint32_t eA_dn = in[base + (ym1 << 10) + xe];
  uint32_t eOwn  = in[base + (y << 10) + yeA];
  uint32_t Eself = in[base + (y << 10) + xe];
  uint32_t Eout  = in[base + (y << 10) + xo];

  uint32_t cro = (b << 19) | (y   << 9) | (X8 >> 1);
  uint32_t crm = (b << 19) | (ym1 << 9) | (X8 >> 1);
  uint32_t crp = (b << 19) | (yp1 << 9) | (X8 >> 1);
  uint32_t cwA0 = *(const uint32_t*)(codeA + cro);
  uint32_t cwAm = *(const uint32_t*)(codeA + crm);
  uint32_t cwAp = *(const uint32_t*)(codeA + crp);
  uint32_t bkE  = codeA[(b << 19) | (y << 9) | (xe >> 1)];
  uint32_t cwB  = *(const uint32_t*)(codeB + cro);

  uint32_t nwA0[4], nwAp[4], nwAm[4];
  upd_row(p0,  pp1, pm1, eOwn,  c_a, cwA0, nwA0);   // ta row y
  upd_row(pp1, pp2, p0,  eA_up, c_b, cwAp, nwAp);   // ta row y+1
  upd_row(pm1, p0,  pm2, eA_dn, c_b, cwAm, nwAm);   // ta row y-1

  uint32_t Ert, Elf;
  if (c_b) { Elf = BY(p0, 7); Ert = Eout; }         // xe = X8+8
  else     { Ert = BY(p0, 0); Elf = Eout; }         // xe = X8-1
  uint32_t E1 = upd1(Eself, eA_up, eA_dn, Ert, Elf, bkE);

  uint32_t nwB[4];
#pragma unroll
  for (int k = 0; k < 4; k++) {
    uint32_t self = c_b ? BY(p0, 2 * k + 1) : BY(p0, 2 * k);
    uint32_t lf, rt;
    if (c_b) { lf = nwA0[k];                 rt = (k == 3) ? E1 : nwA0[k + 1]; }
    else     { lf = (k == 0) ? E1 : nwA0[k - 1]; rt = nwA0[k]; }
    nwB[k] = upd1(self, nwAp[k], nwAm[k], rt, lf, (cwB >> (8 * k)) & 0xffu);
  }

  if (!LAST) {
    uint64_t A = 0;
#pragma unroll
    for (int k = 0; k < 4; k++) {
      A |= (uint64_t)nwA0[k] << (8 * (2 * k + (int)c_a));
      A |= (uint64_t)nwB[k]  << (8 * (2 * k + (int)c_b));
    }
    *(uint64_t*)(outids + base + (y << 10) + X8) = A;
  } else {
    float f[8];
#pragma unroll
    for (int j = 0; j < 8; j++) {
      uint32_t bj = (((uint32_t)j & 1u) == c_a) ? nwA0[j >> 1] : nwB[j >> 1];
      f[j] = (float)bj;
    }
    float4 f0 = {f[0], f[1], f[2], f[3]};
    float4 f1 = {f[4], f[5], f[6], f[7]};
    float* op = out + ((size_t)b << 23) + (y << 10) + X8;
    *(float4*)op       = f0;
    *(float4*)(op + 4) = f1;
  }
}

// ----------------------------------------------- fallback (small-ws) kernels
__device__ __forceinline__ void metro_one(uint32_t u, uint32_t sub,
                                          uint8_t* __restrict__ ids,
                                          const float* __restrict__ dHNN,
                                          uint32_t dk0, uint32_t dk1,
                                          uint32_t uk0, uint32_t uk1) {
  uint32_t b = u >> 19;
  uint32_t r = u & 524287u;
  uint32_t y = r >> 9;
  uint32_t i = r & 511u;
  uint32_t x = (i << 1) | ((y + sub) & 1u);
  uint32_t p = (b << 20) | (y << 10) | x;
  float4 dnn = ((const float4*)dHNN)[sub * NHu + u];
  uint32_t d0, d1, u0, u1;
  tf2x32(dk0, dk1, 0u, p, d0, d1);
  uint32_t db = d0 ^ d1;
  tf2x32(uk0, uk1, 0u, p, u0, u1);
  uint32_t ub = u0 ^ u1;
  int   dir = (int)(db & 3u);
  float uu  = __fsub_rn(__uint_as_float((ub >> 9) | 0x3F800000u), 1.0f);
  uint32_t yN = (y + 1) & 1023u, yP = (y - 1) & 1023u;
  uint32_t xN = (x + 1) & 1023u, xP = (x - 1) & 1023u;
  uint32_t base = b << 20;
  uint32_t cc = ids[p];
  uint32_t n0 = ids[base + (yN << 10) + x];
  uint32_t n1 = ids[base + (yP << 10) + x];
  uint32_t n2 = ids[base + (y << 10) + xN];
  uint32_t n3 = ids[base + (y << 10) + xP];
  uint32_t s  = (dir == 0) ? n0 : (dir == 1) ? n1 : (dir == 2) ? n2 : n3;
  float dH_nn = (dir == 0) ? dnn.x : (dir == 1) ? dnn.y : (dir == 2) ? dnn.z : dnn.w;
  int dadh = ((int)(n0 != s) + (int)(n1 != s) + (int)(n2 != s) + (int)(n3 != s))
           - ((int)(n0 != cc) + (int)(n1 != cc) + (int)(n2 != cc) + (int)(n3 != cc));
  float dH = __fadd_rn((float)dadh, dH_nn);
  if (uu < xla_expf(-dH)) ids[p] = (uint8_t)s;
}

__global__ __launch_bounds__(256) void prep4_fb(const float* __restrict__ X,
                                                const float* __restrict__ W,
                                                const float* __restrict__ Bb,
                                                float* __restrict__ dHNN,
                                                uint8_t* __restrict__ ids) {
  int tid = blockIdx.x * 256 + threadIdx.x;
  int e   = tid << 2;
  int b   = e >> 20;
  int yx  = e & (HW - 1);
  int y   = yx >> 10;
  int x0  = yx & 1023;
  int q4  = yx >> 2;
  const float4* xb = (const float4*)(X + ((size_t)b << 23));
  float4 xc[8];
#pragma unroll
  for (int c = 0; c < 8; c++) xc[c] = xb[(c << 18) + q4];
#pragma unroll
  for (int j = 0; j < 4; j++) {
    float4 r;
#pragma unroll
    for (int o = 0; o < 4; o++) {
      float acc = 0.0f;
#pragma unroll
      for (int c = 0; c < 8; c++)
        acc = __fadd_rn(acc, __fmul_rn(((const float*)&xc[c])[j], W[o * 8 + c]));
      ((float*)&r)[o] = __fadd_rn(acc, Bb[o]);
    }
    int xj = x0 + j;
    ((float4*)dHNN)[((xj + y) & 1) * NHu + (uint32_t)((b << 19) | (y << 9) | (xj >> 1))] = r;
  }
  uchar4 v;
  v.x = (uint8_t)(int)xc[0].x; v.y = (uint8_t)(int)xc[0].y;
  v.z = (uint8_t)(int)xc[0].z; v.w = (uint8_t)(int)xc[0].w;
  *(uchar4*)(ids + e) = v;
}

__global__ __launch_bounds__(256) void half_step_fb(uint8_t* __restrict__ ids,
                                                    const float* __restrict__ dHNN,
                                                    uint32_t dk0, uint32_t dk1,
                                                    uint32_t uk0, uint32_t uk1,
                                                    int sub) {
  uint32_t u = blockIdx.x * 256u + threadIdx.x;
  metro_one(u, (uint32_t)sub, ids, dHNN, dk0, dk1, uk0, uk1);
}

__global__ __launch_bounds__(256) void finalize_full_fb(const float* __restrict__ X,
                                                        const uint8_t* __restrict__ ids,
                                                        float* __restrict__ out) {
  int t = blockIdx.x * 256 + threadIdx.x;
  int e = t << 2;
  int c = (e >> 20) & 7;
  float4 r;
  if (c == 0) {
    int b  = e >> 23;
    int yx = e & (HW - 1);
    uchar4 v = *(const uchar4*)(ids + ((size_t)b << 20) + yx);
    r.x = (float)v.x; r.y = (float)v.y; r.z = (float)v.z; r.w = (float)v.w;
  } else {
    r = ((const float4*)X)[t];
  }
  ((float4*)out)[t] = r;
}

// --------------------------------------------------------------------- host
extern "C" void kernel_launch(void* const* d_in, const int* in_sizes, int n_in,
                              void* d_out, int out_size, void* d_ws, size_t ws_size,
                              hipStream_t stream) {
  const float* X  = (const float*)d_in[0];
  const float* W  = (const float*)d_in[1];
  const float* Bb = (const float*)d_in[2];
  float* out = (float*)d_out;

  const size_t CODE_BYTES = (size_t)NHu * 8u;    // 33.5 MB (8 planes)
  const size_t IDS_BYTES  = (size_t)BHWu;        // 8.4 MB each

  // Threefry key chain (partitionable stream; verified rounds 2-13).
  uint32_t bk0 = 0u, bk1 = 42u;
  uint32_t keys[8][2];
  for (uint32_t t = 0; t < 8; t++)
    tf2x32(bk0, bk1, 0u, t, keys[t][0], keys[t][1]);
  uint32_t K[8][4];
  KeysK KK;
  for (int t = 0; t < 8; t++) {
    uint32_t k1a, k1b;
    tf2x32(keys[t][0], keys[t][1], 0u, 0u, k1a, k1b);         // k1 (randint arg)
    tf2x32(keys[t][0], keys[t][1], 0u, 1u, K[t][2], K[t][3]); // k2 -> ukey
    tf2x32(k1a, k1b, 0u, 1u, K[t][0], K[t][1]);               // randint kk2 -> dkey
    KK.d[t][0] = K[t][0]; KK.d[t][1] = K[t][1];
    KK.u[t][0] = K[t][2]; KK.u[t][1] = K[t][3];
  }

  bool ws_ok = ws_size >= CODE_BYTES + 2 * IDS_BYTES;
  if (ws_ok) {
    uint8_t* code = (uint8_t*)d_ws;
    uint8_t* ids0 = (uint8_t*)d_ws + CODE_BYTES;
    uint8_t* ids1 = ids0 + IDS_BYTES;

    prep_all<<<8192, 256, 0, stream>>>(X, W, Bb, code, ids0, out, KK);
    step2_d<0><<<4096, 256, 0, stream>>>(ids0, ids1,
        code + 0 * (size_t)NHu, code + 1 * (size_t)NHu, out);
    step2_d<0><<<4096, 256, 0, stream>>>(ids1, ids0,
        code + 2 * (size_t)NHu, code + 3 * (size_t)NHu, out);
    step2_d<0><<<4096, 256, 0, stream>>>(ids0, ids1,
        code + 4 * (size_t)NHu, code + 5 * (size_t)NHu, out);
    step2_d<1><<<4096, 256, 0, stream>>>(ids1, ids0,
        code + 6 * (size_t)NHu, code + 7 * (size_t)NHu, out);
  } else {
    float*   dHNN = out;                 // dHNN lives in out; ids in ws
    uint8_t* ids  = (uint8_t*)d_ws;
    prep4_fb<<<8192, 256, 0, stream>>>(X, W, Bb, dHNN, ids);
    for (int t = 0; t < 8; t++)
      half_step_fb<<<16384, 256, 0, stream>>>(ids, dHNN,
          K[t][0], K[t][1], K[t][2], K[t][3], t & 1);
    finalize_full_fb<<<65536, 256, 0, stream>>>(X, ids, out);
  }
  (void)in_sizes; (void)n_in; (void)out_size;
}